// Round 2
// baseline (1155.315 us; speedup 1.0000x reference)
//
#include <hip/hip_runtime.h>
#include <cstddef>

// Problem constants (fixed shapes from the reference)
#define NHEADS 16
#define DHEAD  64
#define SEQL   4096
#define NBH    32            // NBATCH * NHEADS
#define PBH_POOL 4064        // rows per BH in pooled-level arrays (levels 1..7)
#define PBH_Y    12256       // rows per BH in ylev (levels 0..7 = 8160, + diag 4096)

// bf16 storage as raw bits (version-independent, exact RNE)
typedef unsigned short bfu;
__device__ inline float b2f(bfu b) { return __uint_as_float(((unsigned)b) << 16); }
__device__ inline bfu f2b(float f) {
    unsigned u = __float_as_uint(f);
    unsigned r = 0x7FFFu + ((u >> 16) & 1u);
    return (bfu)((u + r) >> 16);
}

// ---------------------------------------------------------------------------
// Tiled fp32 GEMM: A[M,1024] @ W[1024,1024]  (K = N = 1024 fixed), fp32 math.
// MODE 0: output bf16 head-split [B,H,L,DH]  (row r = b*4096+l, col n = h*64+d)
// MODE 1: output fp32 row-major [M,1024] with bias add
// Block: 256 threads, 64x64 tile, 4x4 per thread, BK=16.
// ---------------------------------------------------------------------------
template<int MODE>
__global__ __launch_bounds__(256) void gemm_k1024(
    const float* __restrict__ A, const float* __restrict__ W,
    const float* __restrict__ bias, void* __restrict__ outv)
{
    __shared__ float As[16][68];   // transposed: As[k][m]; 68*4B row stride (16B-aligned)
    __shared__ float Bs[16][68];   // Bs[k][n]

    const int tid = threadIdx.x;
    const int tx = tid & 15, ty = tid >> 4;
    const int m0 = blockIdx.y * 64;
    const int n0 = blockIdx.x * 64;

    float c[4][4] = {};

    for (int kt = 0; kt < 1024; kt += 16) {
        {   // stage A tile (64 rows x 16 k), coalesced float4 along k
            int e = tid * 4;
            int m = e >> 4, k = e & 15;
            const float4 a4 = *reinterpret_cast<const float4*>(
                &A[(size_t)(m0 + m) * 1024 + kt + k]);
            As[k+0][m] = a4.x; As[k+1][m] = a4.y; As[k+2][m] = a4.z; As[k+3][m] = a4.w;
        }
        {   // stage B tile (16 k x 64 n), coalesced float4 along n
            int e = tid * 4;
            int k = e >> 6, n = e & 63;
            const float4 b4 = *reinterpret_cast<const float4*>(
                &W[(size_t)(kt + k) * 1024 + n0 + n]);
            *reinterpret_cast<float4*>(&Bs[k][n]) = b4;
        }
        __syncthreads();
        #pragma unroll
        for (int k = 0; k < 16; ++k) {
            float4 av = *reinterpret_cast<float4*>(&As[k][ty * 4]);
            float4 bv = *reinterpret_cast<float4*>(&Bs[k][tx * 4]);
            float a[4] = {av.x, av.y, av.z, av.w};
            float b[4] = {bv.x, bv.y, bv.z, bv.w};
            #pragma unroll
            for (int i = 0; i < 4; ++i)
                #pragma unroll
                for (int j = 0; j < 4; ++j)
                    c[i][j] = fmaf(a[i], b[j], c[i][j]);
        }
        __syncthreads();
    }

    if (MODE == 0) {
        bfu* o = (bfu*)outv;
        #pragma unroll
        for (int i = 0; i < 4; ++i) {
            int r = m0 + ty * 4 + i;
            int b = r >> 12, l = r & 4095;
            int n = n0 + tx * 4;
            int h = n >> 6, d = n & 63;   // j=0..3 stays inside one head (n0,tx*4 mult of 4)
            ushort4 s;
            s.x = f2b(c[i][0]); s.y = f2b(c[i][1]); s.z = f2b(c[i][2]); s.w = f2b(c[i][3]);
            *reinterpret_cast<ushort4*>(
                &o[(((size_t)b * NHEADS + h) * SEQL + l) * DHEAD + d]) = s;
        }
    } else {
        float* o = (float*)outv;
        #pragma unroll
        for (int i = 0; i < 4; ++i) {
            size_t r = (size_t)(m0 + ty * 4 + i);
            #pragma unroll
            for (int j = 0; j < 4; ++j) {
                int n = n0 + tx * 4 + j;
                o[r * 1024 + n] = c[i][j] + bias[n];
            }
        }
    }
}

// ---------------------------------------------------------------------------
// Pool one level (bf16 in/out, fp32 math): q,k mean; v sum.
// ---------------------------------------------------------------------------
__global__ __launch_bounds__(256) void pool2x(
    const bfu* __restrict__ sq, const bfu* __restrict__ sk, const bfu* __restrict__ sv,
    bfu* __restrict__ dq, bfu* __restrict__ dk, bfu* __restrict__ dv,
    int srcPerBH, int srcRow0, int dstRow0, int dstRows)
{
    int total4 = NBH * dstRows * 16;            // groups of 4 elems
    int g = blockIdx.x * 256 + threadIdx.x;
    if (g >= total4) return;
    int per = dstRows * 16;
    int bh = g / per, f = g % per;
    int r = f >> 4, cc = (f & 15) * 4;
    size_t s0 = ((size_t)bh * srcPerBH + srcRow0 + 2 * r) * 64 + cc;
    size_t di = ((size_t)bh * PBH_POOL + dstRow0 + r) * 64 + cc;

    ushort4 a, b, o;
    a = *reinterpret_cast<const ushort4*>(&sq[s0]);
    b = *reinterpret_cast<const ushort4*>(&sq[s0 + 64]);
    o.x = f2b((b2f(a.x) + b2f(b.x)) * 0.5f);
    o.y = f2b((b2f(a.y) + b2f(b.y)) * 0.5f);
    o.z = f2b((b2f(a.z) + b2f(b.z)) * 0.5f);
    o.w = f2b((b2f(a.w) + b2f(b.w)) * 0.5f);
    *reinterpret_cast<ushort4*>(&dq[di]) = o;

    a = *reinterpret_cast<const ushort4*>(&sk[s0]);
    b = *reinterpret_cast<const ushort4*>(&sk[s0 + 64]);
    o.x = f2b((b2f(a.x) + b2f(b.x)) * 0.5f);
    o.y = f2b((b2f(a.y) + b2f(b.y)) * 0.5f);
    o.z = f2b((b2f(a.z) + b2f(b.z)) * 0.5f);
    o.w = f2b((b2f(a.w) + b2f(b.w)) * 0.5f);
    *reinterpret_cast<ushort4*>(&dk[di]) = o;

    a = *reinterpret_cast<const ushort4*>(&sv[s0]);
    b = *reinterpret_cast<const ushort4*>(&sv[s0 + 64]);
    o.x = f2b(b2f(a.x) + b2f(b.x));
    o.y = f2b(b2f(a.y) + b2f(b.y));
    o.z = f2b(b2f(a.z) + b2f(b.z));
    o.w = f2b(b2f(a.w) + b2f(b.w));
    *reinterpret_cast<ushort4*>(&dv[di]) = o;
}

// ---------------------------------------------------------------------------
// One 16x16 attention block per workgroup (64 threads = 1 wave), fp32 math.
// slots 0..509: levels 0..7 (k/v from swapped neighbor block, nb^1)
// slots 510..765: finest diagonal (no swap)
// Writes un-normalized y (16x64, bf16) and row-sums A (fp32).
// ---------------------------------------------------------------------------
__global__ __launch_bounds__(64) void block_attn(
    const bfu* __restrict__ Q0, const bfu* __restrict__ K0, const bfu* __restrict__ V0,
    const bfu* __restrict__ Qp, const bfu* __restrict__ Kp, const bfu* __restrict__ Vp,
    bfu* __restrict__ ylev, float* __restrict__ Alev)
{
    const int bh = blockIdx.y;
    int slot = blockIdx.x;

    int lvl, nb;
    bool diag = false;
    if (slot >= 510) { diag = true; lvl = 0; nb = slot - 510; }
    else {
        lvl = 0;
        int start = 0;
        while (slot >= start + (256 >> lvl)) { start += (256 >> lvl); ++lvl; }
        nb = slot - start;
    }

    const bfu *q, *k, *v;
    int perbh, loff;
    if (lvl == 0) { q = Q0; k = K0; v = V0; perbh = SEQL; loff = 0; }
    else          { q = Qp; k = Kp; v = Vp; perbh = PBH_POOL; loff = 4096 - (8192 >> lvl); }

    const int qrow0 = loff + nb * 16;
    const int krow0 = loff + (diag ? nb : (nb ^ 1)) * 16;
    const int yrow0 = (diag ? 8160 : (8192 - (8192 >> lvl))) + nb * 16;

    __shared__ float qs[16][68], ks[16][68], vs[16][68];
    __shared__ float ls[16][17];
    __shared__ float red[16];

    const int t = threadIdx.x;
    const bfu* qb = q + ((size_t)bh * perbh + qrow0) * 64;
    const bfu* kb = k + ((size_t)bh * perbh + krow0) * 64;
    const bfu* vb = v + ((size_t)bh * perbh + krow0) * 64;

    #pragma unroll
    for (int j = 0; j < 4; ++j) {
        int f = t + j * 64;                 // group id: row=f>>4, col4=f&15
        int r = f >> 4, cc = (f & 15) * 4;
        ushort4 a;
        a = *reinterpret_cast<const ushort4*>(&qb[r*64 + cc]);
        qs[r][cc] = b2f(a.x); qs[r][cc+1] = b2f(a.y); qs[r][cc+2] = b2f(a.z); qs[r][cc+3] = b2f(a.w);
        a = *reinterpret_cast<const ushort4*>(&kb[r*64 + cc]);
        ks[r][cc] = b2f(a.x); ks[r][cc+1] = b2f(a.y); ks[r][cc+2] = b2f(a.z); ks[r][cc+3] = b2f(a.w);
        a = *reinterpret_cast<const ushort4*>(&vb[r*64 + cc]);
        vs[r][cc] = b2f(a.x); vs[r][cc+1] = b2f(a.y); vs[r][cc+2] = b2f(a.z); vs[r][cc+3] = b2f(a.w);
    }
    __syncthreads();

    // logits: thread t covers col c = t&15, rows (t>>4)+4i
    const float scale = 0.125f;
    const int cc = t & 15;
    float lg[4];
    #pragma unroll
    for (int i = 0; i < 4; ++i) {
        int r = (t >> 4) + i * 4;
        float acc = 0.f;
        #pragma unroll
        for (int d = 0; d < 64; ++d) acc = fmaf(qs[r][d], ks[cc][d], acc);
        lg[i] = acc * scale;
        ls[r][cc] = lg[i];
    }
    __syncthreads();

    if (t < 16) {
        float m = ls[t][0];
        #pragma unroll
        for (int j = 1; j < 16; ++j) m = fmaxf(m, ls[t][j]);
        red[t] = m;
    }
    __syncthreads();

    #pragma unroll
    for (int i = 0; i < 4; ++i) {
        int r = (t >> 4) + i * 4;
        ls[r][cc] = __expf(lg[i] - red[r]);
    }
    __syncthreads();

    if (t < 16) {
        float s = 0.f;
        #pragma unroll
        for (int j = 0; j < 16; ++j) s += ls[t][j];
        Alev[(size_t)bh * PBH_Y + yrow0 + t] = s;
    }

    // y = A @ v : thread t computes column t for all 16 rows
    #pragma unroll
    for (int i = 0; i < 16; ++i) {
        float acc = 0.f;
        #pragma unroll
        for (int kk = 0; kk < 16; ++kk) acc = fmaf(ls[i][kk], vs[kk][t], acc);
        ylev[((size_t)bh * PBH_Y + yrow0 + i) * 64 + t] = f2b(acc);
    }
}

// ---------------------------------------------------------------------------
// Gather the 9 contributions per fine row, normalize, transpose to [B,L,H*DH]
// ---------------------------------------------------------------------------
__global__ __launch_bounds__(256) void gather_norm(
    const bfu* __restrict__ ylev, const float* __restrict__ Alev, float* __restrict__ attn)
{
    int g = blockIdx.x * 256 + threadIdx.x;        // one per (bh,l,d)
    int bh = g >> 18;
    int rem = g & ((1 << 18) - 1);
    int l = rem >> 6, d = rem & 63;
    const bfu* yb = ylev + (size_t)bh * PBH_Y * 64;
    const float* ab = Alev + (size_t)bh * PBH_Y;

    float ys = 0.f, as = 0.f;
    #pragma unroll
    for (int lvl = 0; lvl < 8; ++lvl) {
        int r = (8192 - (8192 >> lvl)) + (l >> lvl);
        ys += b2f(yb[(size_t)r * 64 + d]);
        as += ab[r];
    }
    int rd = 8160 + l;
    ys += b2f(yb[(size_t)rd * 64 + d]);
    as += ab[rd];

    int b = bh >> 4, h = bh & 15;
    attn[((size_t)b * SEQL + l) * 1024 + h * 64 + d] = ys / (as + 1e-12f);
}

// ---------------------------------------------------------------------------
extern "C" void kernel_launch(void* const* d_in, const int* in_sizes, int n_in,
                              void* d_out, int out_size, void* d_ws, size_t ws_size,
                              hipStream_t stream)
{
    const float* q  = (const float*)d_in[0];
    const float* Wq = (const float*)d_in[1];
    const float* Wk = (const float*)d_in[2];
    const float* Wv = (const float*)d_in[3];
    const float* Wo = (const float*)d_in[4];
    const float* bo = (const float*)d_in[5];
    float* out = (float*)d_out;

    // workspace layout — bf16 intermediates, 152,039,424 bytes total (~145 MiB)
    const size_t NE0 = (size_t)NBH * SEQL * 64;      // 8,388,608
    const size_t NEP = (size_t)NBH * PBH_POOL * 64;  // 8,323,072
    const size_t NEY = (size_t)NBH * PBH_Y * 64;     // 25,100,288
    bfu* Qb   = (bfu*)d_ws;
    bfu* Kb   = Qb + NE0;
    bfu* Vb   = Kb + NE0;
    bfu* Qp   = Vb + NE0;
    bfu* Kp   = Qp + NEP;
    bfu* Vp   = Kp + NEP;
    bfu* ylev = Vp + NEP;
    float* Alev = (float*)(ylev + NEY);
    // fp32 attn (32 MiB) overlays Qp/Kp/start-of-Vp (dead after block_attn)
    float* attn = (float*)Qp;

    dim3 gg(16, 128);  // N/64, M/64
    gemm_k1024<0><<<gg, 256, 0, stream>>>(q, Wq, nullptr, Qb);
    gemm_k1024<0><<<gg, 256, 0, stream>>>(q, Wk, nullptr, Kb);
    gemm_k1024<0><<<gg, 256, 0, stream>>>(q, Wv, nullptr, Vb);

    for (int lvl = 1; lvl < 8; ++lvl) {
        int Ld = 4096 >> lvl;
        int srcPerBH = (lvl == 1) ? SEQL : PBH_POOL;
        int srcRow0  = (lvl == 1) ? 0 : (4096 - (8192 >> (lvl - 1)));
        int dstRow0  = 4096 - (8192 >> lvl);
        const bfu* sq = (lvl == 1) ? Qb : Qp;
        const bfu* sk = (lvl == 1) ? Kb : Kp;
        const bfu* sv = (lvl == 1) ? Vb : Vp;
        int total4 = NBH * Ld * 16;
        int nblk = (total4 + 255) / 256;
        pool2x<<<nblk, 256, 0, stream>>>(sq, sk, sv, Qp, Kp, Vp,
                                         srcPerBH, srcRow0, dstRow0, Ld);
    }

    block_attn<<<dim3(766, NBH), 64, 0, stream>>>(Qb, Kb, Vb, Qp, Kp, Vp, ylev, Alev);
    gather_norm<<<32768, 256, 0, stream>>>(ylev, Alev, attn);
    gemm_k1024<1><<<gg, 256, 0, stream>>>(attn, Wo, bo, out);
}

// Round 3
// 371.613 us; speedup vs baseline: 3.1089x; 3.1089x over previous
//
#include <hip/hip_runtime.h>
#include <cstddef>
#include <cstdint>

#define NHEADS 16
#define DHEAD  64
#define SEQL   4096
#define NBH    32            // batch*heads
#define PBH_POOL 4064        // pooled rows per BH (levels 1..7)

typedef unsigned short bfu;
typedef __attribute__((ext_vector_type(4))) float f32x4;
typedef __attribute__((ext_vector_type(8))) short bf16x8;

__device__ inline float b2f(bfu b) { return __uint_as_float(((unsigned)b) << 16); }
__device__ inline bfu f2b(float f) {
    unsigned u = __float_as_uint(f);
    unsigned r = 0x7FFFu + ((u >> 16) & 1u);
    return (bfu)((u + r) >> 16);
}

// ---------------------------------------------------------------------------
// fp32 -> bf16 convert (q matrix, 8192x1024)
// ---------------------------------------------------------------------------
__global__ __launch_bounds__(256) void cvt_q(const float* __restrict__ q, bfu* __restrict__ qb)
{
    size_t g = (size_t)blockIdx.x * 256 + threadIdx.x;   // 2,097,152 threads x 4 elems
    float4 v = *reinterpret_cast<const float4*>(&q[g * 4]);
    ushort4 s;
    s.x = f2b(v.x); s.y = f2b(v.y); s.z = f2b(v.z); s.w = f2b(v.w);
    *reinterpret_cast<ushort4*>(&qb[g * 4]) = s;
}

// ---------------------------------------------------------------------------
// Transpose+convert the 4 weights (1024x1024 fp32) -> Wt[widx][n][k] bf16
// ---------------------------------------------------------------------------
__global__ __launch_bounds__(256) void transpose_cvt(
    const float* __restrict__ W0, const float* __restrict__ W1,
    const float* __restrict__ W2, const float* __restrict__ W3,
    bfu* __restrict__ Wt)
{
    __shared__ float t[32][33];
    const int widx = blockIdx.z;
    const float* src = (widx == 0) ? W0 : (widx == 1) ? W1 : (widx == 2) ? W2 : W3;
    bfu* dst = Wt + (size_t)widx * 1048576;
    const int k0 = blockIdx.y * 32, n0 = blockIdx.x * 32;
    const int tx = threadIdx.x & 31, ty = threadIdx.x >> 5;   // 32 x 8
    #pragma unroll
    for (int i = 0; i < 4; ++i)
        t[ty + 8 * i][tx] = src[(size_t)(k0 + ty + 8 * i) * 1024 + n0 + tx];
    __syncthreads();
    #pragma unroll
    for (int i = 0; i < 4; ++i)
        dst[(size_t)(n0 + ty + 8 * i) * 1024 + k0 + tx] = f2b(t[tx][ty + 8 * i]);
}

// ---------------------------------------------------------------------------
// bf16 MFMA GEMM: C[M,N] = A[M,1024] @ Bt[N,1024]^T, K=1024.
// 128x128 tile, 256 thr = 4 waves (2x2), 4x4 frags of 16x16x32 per wave.
// LDS [128][32] bf16 per operand, XOR-swizzled slots (T2) for conflict-free
// ds_read_b128 fragment loads. Reg-staged (global->reg->swizzled ds_write).
// MODE 0: N=3072 fused QKV; bf16 out, head-split [B,H,L,DH] into O0/O1/O2.
// MODE 1: N=1024; fp32 out row-major + bias.
// ---------------------------------------------------------------------------
template<int MODE>
__global__ __launch_bounds__(256) void gemm_mfma(
    const bfu* __restrict__ A, const bfu* __restrict__ Bt,
    bfu* __restrict__ O0, bfu* __restrict__ O1, bfu* __restrict__ O2,
    float* __restrict__ Ofp, const float* __restrict__ bias)
{
    __shared__ bfu As[128 * 32];
    __shared__ bfu Bs[128 * 32];
    const int tid = threadIdx.x;
    const int lane = tid & 63;
    const int wv = tid >> 6;
    const int wr = wv >> 1, wc = wv & 1;
    const int m0 = blockIdx.y * 128, n0 = blockIdx.x * 128;
    const int rlo = lane & 15, khi = lane >> 4;

    f32x4 acc[4][4];
    #pragma unroll
    for (int i = 0; i < 4; ++i)
        #pragma unroll
        for (int j = 0; j < 4; ++j)
            #pragma unroll
            for (int e = 0; e < 4; ++e) acc[i][j][e] = 0.f;

    for (int kt = 0; kt < 1024; kt += 32) {
        #pragma unroll
        for (int r = 0; r < 2; ++r) {
            int o = (r * 256 + tid) * 16;        // linear byte in 8192-B tile
            int row = o >> 6;                    // 64 B per row (32 bf16)
            int slot = (o >> 4) & 3;             // 16-B slot within row
            int ds = slot ^ ((row >> 1) & 3);    // swizzled dest slot
            uint4 av = *reinterpret_cast<const uint4*>(
                &A[(size_t)(m0 + row) * 1024 + kt + slot * 8]);
            uint4 bv = *reinterpret_cast<const uint4*>(
                &Bt[(size_t)(n0 + row) * 1024 + kt + slot * 8]);
            *reinterpret_cast<uint4*>(reinterpret_cast<char*>(As) + row * 64 + ds * 16) = av;
            *reinterpret_cast<uint4*>(reinterpret_cast<char*>(Bs) + row * 64 + ds * 16) = bv;
        }
        __syncthreads();
        bf16x8 af[4], bf_[4];
        #pragma unroll
        for (int mf = 0; mf < 4; ++mf) {
            int row = wr * 64 + mf * 16 + rlo;
            af[mf] = *reinterpret_cast<const bf16x8*>(
                reinterpret_cast<char*>(As) + row * 64 + ((khi ^ ((row >> 1) & 3)) << 4));
        }
        #pragma unroll
        for (int nf = 0; nf < 4; ++nf) {
            int row = wc * 64 + nf * 16 + rlo;
            bf_[nf] = *reinterpret_cast<const bf16x8*>(
                reinterpret_cast<char*>(Bs) + row * 64 + ((khi ^ ((row >> 1) & 3)) << 4));
        }
        #pragma unroll
        for (int mf = 0; mf < 4; ++mf)
            #pragma unroll
            for (int nf = 0; nf < 4; ++nf)
                acc[mf][nf] = __builtin_amdgcn_mfma_f32_16x16x32_bf16(
                    af[mf], bf_[nf], acc[mf][nf], 0, 0, 0);
        __syncthreads();
    }

    if (MODE == 0) {
        #pragma unroll
        for (int mf = 0; mf < 4; ++mf) {
            #pragma unroll
            for (int nf = 0; nf < 4; ++nf) {
                int np = n0 + wc * 64 + nf * 16 + rlo;
                int wsel = np >> 10, n = np & 1023;
                int h = n >> 6, d = n & 63;
                bfu* O = (wsel == 0) ? O0 : ((wsel == 1) ? O1 : O2);
                #pragma unroll
                for (int rr = 0; rr < 4; ++rr) {
                    int m = m0 + wr * 64 + mf * 16 + khi * 4 + rr;
                    int b = m >> 12, l = m & 4095;
                    O[(((size_t)(b * NHEADS + h)) * SEQL + l) * DHEAD + d] = f2b(acc[mf][nf][rr]);
                }
            }
        }
    } else {
        #pragma unroll
        for (int mf = 0; mf < 4; ++mf) {
            #pragma unroll
            for (int nf = 0; nf < 4; ++nf) {
                int np = n0 + wc * 64 + nf * 16 + rlo;
                float bb = bias[np];
                #pragma unroll
                for (int rr = 0; rr < 4; ++rr) {
                    int m = m0 + wr * 64 + mf * 16 + khi * 4 + rr;
                    Ofp[(size_t)m * 1024 + np] = acc[mf][nf][rr] + bb;
                }
            }
        }
    }
}

// ---------------------------------------------------------------------------
// Pool one level (bf16 in/out, fp32 math): q,k mean; v sum.
// ---------------------------------------------------------------------------
__global__ __launch_bounds__(256) void pool2x(
    const bfu* __restrict__ sq, const bfu* __restrict__ sk, const bfu* __restrict__ sv,
    bfu* __restrict__ dq, bfu* __restrict__ dk, bfu* __restrict__ dv,
    int srcPerBH, int srcRow0, int dstRow0, int dstRows)
{
    int total4 = NBH * dstRows * 16;
    int g = blockIdx.x * 256 + threadIdx.x;
    if (g >= total4) return;
    int per = dstRows * 16;
    int bh = g / per, f = g % per;
    int r = f >> 4, cc = (f & 15) * 4;
    size_t s0 = ((size_t)bh * srcPerBH + srcRow0 + 2 * r) * 64 + cc;
    size_t di = ((size_t)bh * PBH_POOL + dstRow0 + r) * 64 + cc;

    ushort4 a, b, o;
    a = *reinterpret_cast<const ushort4*>(&sq[s0]);
    b = *reinterpret_cast<const ushort4*>(&sq[s0 + 64]);
    o.x = f2b((b2f(a.x) + b2f(b.x)) * 0.5f);
    o.y = f2b((b2f(a.y) + b2f(b.y)) * 0.5f);
    o.z = f2b((b2f(a.z) + b2f(b.z)) * 0.5f);
    o.w = f2b((b2f(a.w) + b2f(b.w)) * 0.5f);
    *reinterpret_cast<ushort4*>(&dq[di]) = o;

    a = *reinterpret_cast<const ushort4*>(&sk[s0]);
    b = *reinterpret_cast<const ushort4*>(&sk[s0 + 64]);
    o.x = f2b((b2f(a.x) + b2f(b.x)) * 0.5f);
    o.y = f2b((b2f(a.y) + b2f(b.y)) * 0.5f);
    o.z = f2b((b2f(a.z) + b2f(b.z)) * 0.5f);
    o.w = f2b((b2f(a.w) + b2f(b.w)) * 0.5f);
    *reinterpret_cast<ushort4*>(&dk[di]) = o;

    a = *reinterpret_cast<const ushort4*>(&sv[s0]);
    b = *reinterpret_cast<const ushort4*>(&sv[s0 + 64]);
    o.x = f2b(b2f(a.x) + b2f(b.x));
    o.y = f2b(b2f(a.y) + b2f(b.y));
    o.z = f2b(b2f(a.z) + b2f(b.z));
    o.w = f2b(b2f(a.w) + b2f(b.w));
    *reinterpret_cast<ushort4*>(&dv[di]) = o;
}

// ---------------------------------------------------------------------------
// One q-block per workgroup (64 thr). slots 0..255: level 0, TWO k-blocks
// (neighbor nb^1 + diagonal nb, summed unnormalized). slots 256..509:
// levels 1..7, k-block nb^1. Level-0 y goes directly to attn layout (y0);
// levels 1..7 go to ylev/Alev at pooled-row indexing.
// ---------------------------------------------------------------------------
__global__ __launch_bounds__(64) void block_attn(
    const bfu* __restrict__ Q0, const bfu* __restrict__ K0, const bfu* __restrict__ V0,
    const bfu* __restrict__ Qp, const bfu* __restrict__ Kp, const bfu* __restrict__ Vp,
    bfu* __restrict__ y0, float* __restrict__ A0,
    bfu* __restrict__ ylev, float* __restrict__ Alev)
{
    const int bh = blockIdx.y;
    const int slot = blockIdx.x;
    int lvl, nb;
    if (slot < 256) { lvl = 0; nb = slot; }
    else {
        lvl = 1; int start = 256, cnt = 128;
        while (slot >= start + cnt) { start += cnt; cnt >>= 1; ++lvl; }
        nb = slot - start;
    }
    const bfu *q, *k, *v; int perbh, loff;
    if (lvl == 0) { q = Q0; k = K0; v = V0; perbh = SEQL; loff = 0; }
    else          { q = Qp; k = Kp; v = Vp; perbh = PBH_POOL; loff = 4096 - (8192 >> lvl); }
    const int qrow0 = loff + nb * 16;

    __shared__ float qs[16][68], ks[16][68], vs[16][68];
    __shared__ float ls[16][17];
    __shared__ float red[16];
    const int t = threadIdx.x;

    { // stage q once
        const bfu* qp_ = q + ((size_t)bh * perbh + qrow0) * 64;
        #pragma unroll
        for (int j = 0; j < 4; ++j) {
            int f = t + j * 64;
            int r = f >> 4, cc = (f & 15) * 4;
            ushort4 a = *reinterpret_cast<const ushort4*>(&qp_[r * 64 + cc]);
            qs[r][cc] = b2f(a.x); qs[r][cc+1] = b2f(a.y);
            qs[r][cc+2] = b2f(a.z); qs[r][cc+3] = b2f(a.w);
        }
    }

    float yacc[16];
    #pragma unroll
    for (int i = 0; i < 16; ++i) yacc[i] = 0.f;
    float Aacc = 0.f;

    const int npass = (lvl == 0) ? 2 : 1;
    for (int pass = 0; pass < npass; ++pass) {
        const int kbi = (lvl == 0) ? ((pass == 0) ? (nb ^ 1) : nb) : (nb ^ 1);
        const int krow0 = loff + kbi * 16;
        const bfu* kp_ = k + ((size_t)bh * perbh + krow0) * 64;
        const bfu* vp_ = v + ((size_t)bh * perbh + krow0) * 64;
        #pragma unroll
        for (int j = 0; j < 4; ++j) {
            int f = t + j * 64;
            int r = f >> 4, cc = (f & 15) * 4;
            ushort4 a = *reinterpret_cast<const ushort4*>(&kp_[r * 64 + cc]);
            ks[r][cc] = b2f(a.x); ks[r][cc+1] = b2f(a.y);
            ks[r][cc+2] = b2f(a.z); ks[r][cc+3] = b2f(a.w);
            a = *reinterpret_cast<const ushort4*>(&vp_[r * 64 + cc]);
            vs[r][cc] = b2f(a.x); vs[r][cc+1] = b2f(a.y);
            vs[r][cc+2] = b2f(a.z); vs[r][cc+3] = b2f(a.w);
        }
        __syncthreads();

        const float scale = 0.125f;
        const int cc = t & 15;
        float lg[4];
        #pragma unroll
        for (int i = 0; i < 4; ++i) {
            int r = (t >> 4) + i * 4;
            float acc = 0.f;
            #pragma unroll
            for (int d = 0; d < 64; ++d) acc = fmaf(qs[r][d], ks[cc][d], acc);
            lg[i] = acc * scale;
            ls[r][cc] = lg[i];
        }
        __syncthreads();
        if (t < 16) {
            float m = ls[t][0];
            #pragma unroll
            for (int j = 1; j < 16; ++j) m = fmaxf(m, ls[t][j]);
            red[t] = m;
        }
        __syncthreads();
        #pragma unroll
        for (int i = 0; i < 4; ++i) {
            int r = (t >> 4) + i * 4;
            ls[r][cc] = __expf(lg[i] - red[r]);
        }
        __syncthreads();
        if (t < 16) {
            float s = 0.f;
            #pragma unroll
            for (int j = 0; j < 16; ++j) s += ls[t][j];
            Aacc += s;
        }
        #pragma unroll
        for (int i = 0; i < 16; ++i) {
            float acc = 0.f;
            #pragma unroll
            for (int kk = 0; kk < 16; ++kk) acc = fmaf(ls[i][kk], vs[kk][t], acc);
            yacc[i] += acc;
        }
        __syncthreads();   // protect ks/vs/ls before next pass restages
    }

    if (lvl == 0) {
        int b = bh >> 4, h = bh & 15;
        if (t < 16) A0[(size_t)bh * SEQL + nb * 16 + t] = Aacc;
        #pragma unroll
        for (int i = 0; i < 16; ++i)
            y0[((size_t)(b * SEQL + nb * 16 + i)) * 1024 + h * 64 + t] = f2b(yacc[i]);
    } else {
        if (t < 16) Alev[(size_t)bh * PBH_POOL + qrow0 + t] = Aacc;
        #pragma unroll
        for (int i = 0; i < 16; ++i)
            ylev[((size_t)bh * PBH_POOL + qrow0 + i) * 64 + t] = f2b(yacc[i]);
    }
}

// ---------------------------------------------------------------------------
// In-place: attn = (y0 + sum_levels ylev) / (A0 + sum Alev + eps), bf16.
// g is linear over [b][l][h*64+d] == y0 layout, so read/write same address.
// ---------------------------------------------------------------------------
__global__ __launch_bounds__(256) void gather_norm(
    const bfu* __restrict__ ylev, const float* __restrict__ Alev,
    const float* __restrict__ A0, bfu* __restrict__ y0)
{
    size_t g = (size_t)blockIdx.x * 256 + threadIdx.x;
    int d = (int)(g & 63);
    int h = (int)((g >> 6) & 15);
    int l = (int)((g >> 10) & 4095);
    int b = (int)(g >> 22);
    int bh = b * NHEADS + h;

    float ys = b2f(y0[g]);
    float as = A0[(size_t)bh * SEQL + l];
    #pragma unroll
    for (int lvl = 1; lvl <= 7; ++lvl) {
        int r = (4096 - (8192 >> lvl)) + (l >> lvl);
        ys += b2f(ylev[((size_t)bh * PBH_POOL + r) * 64 + d]);
        as += Alev[(size_t)bh * PBH_POOL + r];
    }
    y0[g] = f2b(ys / (as + 1e-12f));
}

// ---------------------------------------------------------------------------
extern "C" void kernel_launch(void* const* d_in, const int* in_sizes, int n_in,
                              void* d_out, int out_size, void* d_ws, size_t ws_size,
                              hipStream_t stream)
{
    const float* q  = (const float*)d_in[0];
    const float* Wq = (const float*)d_in[1];
    const float* Wk = (const float*)d_in[2];
    const float* Wv = (const float*)d_in[3];
    const float* Wo = (const float*)d_in[4];
    const float* bo = (const float*)d_in[5];
    float* out = (float*)d_out;

    // workspace: 143,126,528 B (~136.5 MiB)
    const size_t NE0 = (size_t)NBH * SEQL * 64;      // 8,388,608
    const size_t NEP = (size_t)NBH * PBH_POOL * 64;  // 8,323,072
    bfu* qb   = (bfu*)d_ws;            // bf16 of q; later: y0 / attn (same size)
    bfu* Wt   = qb + NE0;              // 4 transposed weights, 4x1M bf16
    bfu* Qb   = Wt + 4 * 1048576;
    bfu* Kb   = Qb + NE0;
    bfu* Vb   = Kb + NE0;
    bfu* Qp   = Vb + NE0;
    bfu* Kp   = Qp + NEP;
    bfu* Vp   = Kp + NEP;
    bfu* ylev = Vp + NEP;
    float* Alev = (float*)(ylev + NEP);              // 32*4064
    float* A0   = Alev + (size_t)NBH * PBH_POOL;     // 32*4096

    cvt_q<<<8192, 256, 0, stream>>>(q, qb);
    transpose_cvt<<<dim3(32, 32, 4), 256, 0, stream>>>(Wq, Wk, Wv, Wo, Wt);

    // fused QKV: A[8192,1024] @ (Wq|Wk|Wv)  (N=3072)
    gemm_mfma<0><<<dim3(24, 64), 256, 0, stream>>>(
        qb, Wt, Qb, Kb, Vb, nullptr, nullptr);

    for (int lvl = 1; lvl < 8; ++lvl) {
        int Ld = 4096 >> lvl;
        int srcPerBH = (lvl == 1) ? SEQL : PBH_POOL;
        int srcRow0  = (lvl == 1) ? 0 : (4096 - (8192 >> (lvl - 1)));
        int dstRow0  = 4096 - (8192 >> lvl);
        const bfu* sq = (lvl == 1) ? Qb : Qp;
        const bfu* sk = (lvl == 1) ? Kb : Kp;
        const bfu* sv = (lvl == 1) ? Vb : Vp;
        int total4 = NBH * Ld * 16;
        int nblk = (total4 + 255) / 256;
        pool2x<<<nblk, 256, 0, stream>>>(sq, sk, sv, Qp, Kp, Vp,
                                         srcPerBH, srcRow0, dstRow0, Ld);
    }

    block_attn<<<dim3(510, NBH), 64, 0, stream>>>(
        Qb, Kb, Vb, Qp, Kp, Vp, qb /*y0*/, A0, ylev, Alev);

    gather_norm<<<32768, 256, 0, stream>>>(ylev, Alev, A0, qb);

    // out = attn(bf16, in qb) @ Wo + bo   (fp32 out)
    gemm_mfma<1><<<dim3(8, 64), 256, 0, stream>>>(
        qb, Wt + 3 * 1048576, nullptr, nullptr, nullptr, out, bo);
}

// Round 4
// 288.887 us; speedup vs baseline: 3.9992x; 1.2864x over previous
//
#include <hip/hip_runtime.h>
#include <cstddef>
#include <cstdint>

#define NHEADS 16
#define DHEAD  64
#define SEQL   4096
#define NBH    32            // batch*heads
#define PBH_POOL 4064        // pooled rows per BH (levels 1..7)

typedef unsigned short bfu;
typedef unsigned int u32;
typedef __attribute__((ext_vector_type(4)))  float f32x4;
typedef __attribute__((ext_vector_type(16))) float f32x16;
typedef __attribute__((ext_vector_type(8)))  short bf16x8;

__device__ inline float b2f(bfu b) { return __uint_as_float(((unsigned)b) << 16); }
__device__ inline bfu f2b(float f) {
    unsigned u = __float_as_uint(f);
    unsigned r = 0x7FFFu + ((u >> 16) & 1u);
    return (bfu)((u + r) >> 16);
}
__device__ inline u32 pk2(float a, float b) {
    return (u32)f2b(a) | ((u32)f2b(b) << 16);
}
__device__ inline bf16x8 mk8(u32 a, u32 b, u32 c, u32 d) {
    union { u32 u[4]; bf16x8 v; } x;
    x.u[0] = a; x.u[1] = b; x.u[2] = c; x.u[3] = d;
    return x.v;
}

// ---------------------------------------------------------------------------
// fp32 -> bf16 convert (q matrix, 8192x1024)
// ---------------------------------------------------------------------------
__global__ __launch_bounds__(256) void cvt_q(const float* __restrict__ q, bfu* __restrict__ qb)
{
    size_t g = (size_t)blockIdx.x * 256 + threadIdx.x;
    float4 v = *reinterpret_cast<const float4*>(&q[g * 4]);
    ushort4 s;
    s.x = f2b(v.x); s.y = f2b(v.y); s.z = f2b(v.z); s.w = f2b(v.w);
    *reinterpret_cast<ushort4*>(&qb[g * 4]) = s;
}

// ---------------------------------------------------------------------------
// Transpose+convert the 4 weights (1024x1024 fp32) -> Wt[widx][n][k] bf16
// ---------------------------------------------------------------------------
__global__ __launch_bounds__(256) void transpose_cvt(
    const float* __restrict__ W0, const float* __restrict__ W1,
    const float* __restrict__ W2, const float* __restrict__ W3,
    bfu* __restrict__ Wt)
{
    __shared__ float t[32][33];
    const int widx = blockIdx.z;
    const float* src = (widx == 0) ? W0 : (widx == 1) ? W1 : (widx == 2) ? W2 : W3;
    bfu* dst = Wt + (size_t)widx * 1048576;
    const int k0 = blockIdx.y * 32, n0 = blockIdx.x * 32;
    const int tx = threadIdx.x & 31, ty = threadIdx.x >> 5;
    #pragma unroll
    for (int i = 0; i < 4; ++i)
        t[ty + 8 * i][tx] = src[(size_t)(k0 + ty + 8 * i) * 1024 + n0 + tx];
    __syncthreads();
    #pragma unroll
    for (int i = 0; i < 4; ++i)
        dst[(size_t)(n0 + ty + 8 * i) * 1024 + k0 + tx] = f2b(t[tx][ty + 8 * i]);
}

// ---------------------------------------------------------------------------
// bf16 MFMA GEMM, K=1024, 128x128 tile, 4 waves, 4x4x(16x16x32) frags/wave.
// Staging via global_load_lds width=16: LINEAR LDS dest, swizzle applied to
// the GLOBAL source slot (rule 21); fragment reads use the same XOR.
// MODE 0: N=3072 fused QKV -> bf16 head-split [B,H,L,DH] into O0/O1/O2.
// MODE 1: N=1024 -> fp32 row-major + bias.
// ---------------------------------------------------------------------------
template<int MODE>
__global__ __launch_bounds__(256) void gemm_mfma(
    const bfu* __restrict__ A, const bfu* __restrict__ Bt,
    bfu* __restrict__ O0, bfu* __restrict__ O1, bfu* __restrict__ O2,
    float* __restrict__ Ofp, const float* __restrict__ bias)
{
    __shared__ bfu As[128 * 32];
    __shared__ bfu Bs[128 * 32];
    const int tid = threadIdx.x;
    const int lane = tid & 63;
    const int wv = tid >> 6;
    const int wr = wv >> 1, wc = wv & 1;
    const int m0 = blockIdx.y * 128, n0 = blockIdx.x * 128;
    const int rlo = lane & 15, khi = lane >> 4;

    f32x4 acc[4][4];
    #pragma unroll
    for (int i = 0; i < 4; ++i)
        #pragma unroll
        for (int j = 0; j < 4; ++j)
            #pragma unroll
            for (int e = 0; e < 4; ++e) acc[i][j][e] = 0.f;

    for (int kt = 0; kt < 1024; kt += 32) {
        #pragma unroll
        for (int r = 0; r < 2; ++r) {
            int o = (r * 256 + tid) * 16;        // linear byte in 8192-B tile
            int row = o >> 6;                    // 64 B per row (32 bf16)
            int slot = (o >> 4) & 3;
            int sg = slot ^ ((row >> 1) & 3);    // pre-swizzled SOURCE slot
            __builtin_amdgcn_global_load_lds(
                (const __attribute__((address_space(1))) u32*)
                    &A[(size_t)(m0 + row) * 1024 + kt + sg * 8],
                (__attribute__((address_space(3))) u32*)
                    (reinterpret_cast<char*>(As) + o), 16, 0, 0);
            __builtin_amdgcn_global_load_lds(
                (const __attribute__((address_space(1))) u32*)
                    &Bt[(size_t)(n0 + row) * 1024 + kt + sg * 8],
                (__attribute__((address_space(3))) u32*)
                    (reinterpret_cast<char*>(Bs) + o), 16, 0, 0);
        }
        __syncthreads();
        bf16x8 af[4], bf_[4];
        #pragma unroll
        for (int mf = 0; mf < 4; ++mf) {
            int row = wr * 64 + mf * 16 + rlo;
            af[mf] = *reinterpret_cast<const bf16x8*>(
                reinterpret_cast<char*>(As) + row * 64 + ((khi ^ ((row >> 1) & 3)) << 4));
        }
        #pragma unroll
        for (int nf = 0; nf < 4; ++nf) {
            int row = wc * 64 + nf * 16 + rlo;
            bf_[nf] = *reinterpret_cast<const bf16x8*>(
                reinterpret_cast<char*>(Bs) + row * 64 + ((khi ^ ((row >> 1) & 3)) << 4));
        }
        #pragma unroll
        for (int mf = 0; mf < 4; ++mf)
            #pragma unroll
            for (int nf = 0; nf < 4; ++nf)
                acc[mf][nf] = __builtin_amdgcn_mfma_f32_16x16x32_bf16(
                    af[mf], bf_[nf], acc[mf][nf], 0, 0, 0);
        __syncthreads();
    }

    if (MODE == 0) {
        #pragma unroll
        for (int mf = 0; mf < 4; ++mf) {
            #pragma unroll
            for (int nf = 0; nf < 4; ++nf) {
                int np = n0 + wc * 64 + nf * 16 + rlo;
                int wsel = np >> 10, n = np & 1023;
                int h = n >> 6, d = n & 63;
                bfu* O = (wsel == 0) ? O0 : ((wsel == 1) ? O1 : O2);
                #pragma unroll
                for (int rr = 0; rr < 4; ++rr) {
                    int m = m0 + wr * 64 + mf * 16 + khi * 4 + rr;
                    int b = m >> 12, l = m & 4095;
                    O[(((size_t)(b * NHEADS + h)) * SEQL + l) * DHEAD + d] = f2b(acc[mf][nf][rr]);
                }
            }
        }
    } else {
        #pragma unroll
        for (int mf = 0; mf < 4; ++mf) {
            #pragma unroll
            for (int nf = 0; nf < 4; ++nf) {
                int np = n0 + wc * 64 + nf * 16 + rlo;
                float bb = bias[np];
                #pragma unroll
                for (int rr = 0; rr < 4; ++rr) {
                    int m = m0 + wr * 64 + mf * 16 + khi * 4 + rr;
                    Ofp[(size_t)m * 1024 + np] = acc[mf][nf][rr] + bb;
                }
            }
        }
    }
}

// ---------------------------------------------------------------------------
// Level-0 V transpose: Vb[bh][l][d] -> Vt0[bh][d][l].  64x64 tiles, LDS with
// XOR-swizzled columns (phys_col = col ^ ((d>>3)*8)) -> conflict-free.
// ---------------------------------------------------------------------------
__global__ __launch_bounds__(256) void transpose_v(
    const bfu* __restrict__ Vb, bfu* __restrict__ Vt0)
{
    __shared__ bfu tile[64 * 64];
    const int bh = blockIdx.y, l0 = blockIdx.x * 64;
    const int t = threadIdx.x;
    const int row = t >> 3, chunk = t & 7;
    #pragma unroll
    for (int it = 0; it < 2; ++it) {
        int r = it * 32 + row;
        uint4 v = *reinterpret_cast<const uint4*>(
            &Vb[((size_t)bh * SEQL + l0 + r) * 64 + chunk * 8]);
        bfu e[8];
        e[0] = v.x & 0xffff; e[1] = v.x >> 16; e[2] = v.y & 0xffff; e[3] = v.y >> 16;
        e[4] = v.z & 0xffff; e[5] = v.z >> 16; e[6] = v.w & 0xffff; e[7] = v.w >> 16;
        int pr = r ^ (chunk * 8);   // phys col; d>>3 == chunk for all 8 elems
        #pragma unroll
        for (int j = 0; j < 8; ++j) tile[(chunk * 8 + j) * 64 + pr] = e[j];
    }
    __syncthreads();
    #pragma unroll
    for (int it = 0; it < 2; ++it) {
        int d = it * 32 + (t >> 3);
        int lc = t & 7;
        int plc = lc ^ (d >> 3);
        uint4 v = *reinterpret_cast<const uint4*>(&tile[d * 64 + plc * 8]);
        *reinterpret_cast<uint4*>(
            &Vt0[((size_t)bh * 64 + d) * SEQL + l0 + lc * 8]) = v;
    }
}

// ---------------------------------------------------------------------------
// Pool one level: q,k mean in row-major; v sum in TRANSPOSED (d-major) space.
// ---------------------------------------------------------------------------
__global__ __launch_bounds__(256) void pool2x(
    const bfu* __restrict__ sq, const bfu* __restrict__ sk, const bfu* __restrict__ svt,
    bfu* __restrict__ dq, bfu* __restrict__ dk, bfu* __restrict__ dvt,
    int srcPerBH, int srcRow0, int dstRow0, int dstRows, int svtCols)
{
    int g = blockIdx.x * 256 + threadIdx.x;
    int half = NBH * dstRows * 16;
    if (g < half) {
        int per = dstRows * 16;
        int bh = g / per, f = g % per;
        int r = f >> 4, cc = (f & 15) * 4;
        size_t s0 = ((size_t)bh * srcPerBH + srcRow0 + 2 * r) * 64 + cc;
        size_t di = ((size_t)bh * PBH_POOL + dstRow0 + r) * 64 + cc;
        ushort4 a, b, o;
        a = *reinterpret_cast<const ushort4*>(&sq[s0]);
        b = *reinterpret_cast<const ushort4*>(&sq[s0 + 64]);
        o.x = f2b((b2f(a.x) + b2f(b.x)) * 0.5f);
        o.y = f2b((b2f(a.y) + b2f(b.y)) * 0.5f);
        o.z = f2b((b2f(a.z) + b2f(b.z)) * 0.5f);
        o.w = f2b((b2f(a.w) + b2f(b.w)) * 0.5f);
        *reinterpret_cast<ushort4*>(&dq[di]) = o;
        a = *reinterpret_cast<const ushort4*>(&sk[s0]);
        b = *reinterpret_cast<const ushort4*>(&sk[s0 + 64]);
        o.x = f2b((b2f(a.x) + b2f(b.x)) * 0.5f);
        o.y = f2b((b2f(a.y) + b2f(b.y)) * 0.5f);
        o.z = f2b((b2f(a.z) + b2f(b.z)) * 0.5f);
        o.w = f2b((b2f(a.w) + b2f(b.w)) * 0.5f);
        *reinterpret_cast<ushort4*>(&dk[di]) = o;
    } else {
        g -= half;
        int nr4 = dstRows >> 2;
        int per = 64 * nr4;
        int bh = g / per, f = g % per;
        int d = f / nr4, r4 = (f % nr4) * 4;
        const bfu* srow = svt + ((size_t)bh * 64 + d) * svtCols + srcRow0 + 2 * r4;
        uint4 v = *reinterpret_cast<const uint4*>(srow);
        ushort4 o;
        o.x = f2b(b2f(v.x & 0xffff) + b2f(v.x >> 16));
        o.y = f2b(b2f(v.y & 0xffff) + b2f(v.y >> 16));
        o.z = f2b(b2f(v.z & 0xffff) + b2f(v.z >> 16));
        o.w = f2b(b2f(v.w & 0xffff) + b2f(v.w >> 16));
        *reinterpret_cast<ushort4*>(&dvt[((size_t)bh * 64 + d) * PBH_POOL + dstRow0 + r4]) = o;
    }
}

// ---------------------------------------------------------------------------
// One wave per (bh, block-pair).  S^T = K.Q^T via 4x mfma_32x32x16_bf16
// (C: col=lane&31=q, row kk=(reg&3)+8*(reg>>2)+4*(lane>>5)).  Per-quadrant
// in-register softmax (+shfl_xor 32).  Level 0 keeps all 4 quadrants
// (diag+neighbor fused); levels>=1 zero the diagonal quadrants.
// PV: y^T = V^T.P^T with V in d-major layout -> each lane owns one y row.
// ---------------------------------------------------------------------------
__global__ __launch_bounds__(64) void pair_attn(
    const bfu* __restrict__ Q0, const bfu* __restrict__ K0, const bfu* __restrict__ Vt0,
    const bfu* __restrict__ Qp, const bfu* __restrict__ Kp, const bfu* __restrict__ Vtp,
    bfu* __restrict__ y0, float* __restrict__ A0,
    bfu* __restrict__ ylev, float* __restrict__ Alev)
{
    const int bh = blockIdx.y;
    int s = blockIdx.x, lvl = 0, cnt = 128;
    while (s >= cnt) { s -= cnt; cnt >>= 1; ++lvl; }
    const bfu *Q, *K, *Vt; int perbh, vcols, loff;
    if (lvl == 0) { Q = Q0; K = K0; Vt = Vt0; perbh = SEQL; vcols = SEQL; loff = 0; }
    else { Q = Qp; K = Kp; Vt = Vtp; perbh = PBH_POOL; vcols = PBH_POOL; loff = 4096 - (8192 >> lvl); }
    const int rbase = loff + s * 32;
    const int t = threadIdx.x, q31 = t & 31, hl = t >> 5;

    const bfu* Krow = K + ((size_t)bh * perbh + rbase + q31) * 64 + hl * 8;
    const bfu* Qrow = Q + ((size_t)bh * perbh + rbase + q31) * 64 + hl * 8;

    f32x16 S;
    #pragma unroll
    for (int e = 0; e < 16; ++e) S[e] = 0.f;
    #pragma unroll
    for (int db = 0; db < 4; ++db) {
        bf16x8 ka = *reinterpret_cast<const bf16x8*>(Krow + db * 16);
        bf16x8 qa = *reinterpret_cast<const bf16x8*>(Qrow + db * 16);
        S = __builtin_amdgcn_mfma_f32_32x32x16_bf16(ka, qa, S, 0, 0, 0);
    }

    float p[16];
    #pragma unroll
    for (int r = 0; r < 16; ++r) p[r] = S[r] * 0.125f;
    float mlo = p[0], mhi = p[8];
    #pragma unroll
    for (int r = 1; r < 8; ++r) { mlo = fmaxf(mlo, p[r]); mhi = fmaxf(mhi, p[r + 8]); }
    mlo = fmaxf(mlo, __shfl_xor(mlo, 32));
    mhi = fmaxf(mhi, __shfl_xor(mhi, 32));
    #pragma unroll
    for (int r = 0; r < 8; ++r) {
        p[r]     = __expf(p[r]     - mlo);
        p[r + 8] = __expf(p[r + 8] - mhi);
    }
    if (lvl > 0) {
        #pragma unroll
        for (int r = 0; r < 8; ++r) {
            if (q31 < 16) p[r] = 0.f; else p[r + 8] = 0.f;
        }
    }
    float alo = 0.f, ahi = 0.f;
    #pragma unroll
    for (int r = 0; r < 8; ++r) { alo += p[r]; ahi += p[r + 8]; }
    alo += __shfl_xor(alo, 32);
    ahi += __shfl_xor(ahi, 32);
    const float Asum = alo + ahi;

    // pack P^T into MFMA B operands (lane: col=q, k = kk = 16m + hl*8 + e)
    bf16x8 Pop[2];
    #pragma unroll
    for (int m = 0; m < 2; ++m) {
        u32 a0 = pk2(p[8 * m + 0], p[8 * m + 1]);
        u32 a1 = pk2(p[8 * m + 2], p[8 * m + 3]);
        u32 b0 = pk2(p[8 * m + 4], p[8 * m + 5]);
        u32 b1 = pk2(p[8 * m + 6], p[8 * m + 7]);
        u32 pa0 = __shfl_xor(a0, 32), pa1 = __shfl_xor(a1, 32);
        u32 pb0 = __shfl_xor(b0, 32), pb1 = __shfl_xor(b1, 32);
        Pop[m] = (hl == 0) ? mk8(a0, a1, pa0, pa1) : mk8(pb0, pb1, b0, b1);
    }

    const bfu* Vbase = Vt + (size_t)bh * 64 * vcols + rbase + hl * 8;
    f32x16 y[2];
    #pragma unroll
    for (int tt = 0; tt < 2; ++tt) {
        #pragma unroll
        for (int e = 0; e < 16; ++e) y[tt][e] = 0.f;
        #pragma unroll
        for (int m = 0; m < 2; ++m) {
            bf16x8 va = *reinterpret_cast<const bf16x8*>(
                Vbase + (size_t)(tt * 32 + q31) * vcols + m * 16);
            y[tt] = __builtin_amdgcn_mfma_f32_32x32x16_bf16(va, Pop[m], y[tt], 0, 0, 0);
        }
    }

    if (lvl == 0) {
        const int b = bh >> 4, h = bh & 15;
        bfu* orow = y0 + ((size_t)(b * SEQL + rbase + q31)) * 1024 + h * 64;
        #pragma unroll
        for (int tt = 0; tt < 2; ++tt)
            #pragma unroll
            for (int g = 0; g < 4; ++g) {
                int d0 = tt * 32 + g * 8 + hl * 4;
                ushort4 s4;
                s4.x = f2b(y[tt][4 * g + 0]); s4.y = f2b(y[tt][4 * g + 1]);
                s4.z = f2b(y[tt][4 * g + 2]); s4.w = f2b(y[tt][4 * g + 3]);
                *reinterpret_cast<ushort4*>(orow + d0) = s4;
            }
        if (hl == 0) A0[(size_t)bh * SEQL + rbase + q31] = Asum;
    } else {
        bfu* orow = ylev + ((size_t)bh * PBH_POOL + rbase + q31) * 64;
        #pragma unroll
        for (int tt = 0; tt < 2; ++tt)
            #pragma unroll
            for (int g = 0; g < 4; ++g) {
                int d0 = tt * 32 + g * 8 + hl * 4;
                ushort4 s4;
                s4.x = f2b(y[tt][4 * g + 0]); s4.y = f2b(y[tt][4 * g + 1]);
                s4.z = f2b(y[tt][4 * g + 2]); s4.w = f2b(y[tt][4 * g + 3]);
                *reinterpret_cast<ushort4*>(orow + d0) = s4;
            }
        if (hl == 0) Alev[(size_t)bh * PBH_POOL + rbase + q31] = Asum;
    }
}

// ---------------------------------------------------------------------------
// In-place: attn = (y0 + sum_levels ylev) / (A0 + sum Alev + eps), bf16.
// ---------------------------------------------------------------------------
__global__ __launch_bounds__(256) void gather_norm(
    const bfu* __restrict__ ylev, const float* __restrict__ Alev,
    const float* __restrict__ A0, bfu* __restrict__ y0)
{
    size_t g = (size_t)blockIdx.x * 256 + threadIdx.x;
    int d = (int)(g & 63);
    int h = (int)((g >> 6) & 15);
    int l = (int)((g >> 10) & 4095);
    int b = (int)(g >> 22);
    int bh = b * NHEADS + h;

    float ys = b2f(y0[g]);
    float as = A0[(size_t)bh * SEQL + l];
    #pragma unroll
    for (int lvl = 1; lvl <= 7; ++lvl) {
        int r = (4096 - (8192 >> lvl)) + (l >> lvl);
        ys += b2f(ylev[((size_t)bh * PBH_POOL + r) * 64 + d]);
        as += Alev[(size_t)bh * PBH_POOL + r];
    }
    y0[g] = f2b(ys / (as + 1e-12f));
}

// ---------------------------------------------------------------------------
extern "C" void kernel_launch(void* const* d_in, const int* in_sizes, int n_in,
                              void* d_out, int out_size, void* d_ws, size_t ws_size,
                              hipStream_t stream)
{
    const float* q  = (const float*)d_in[0];
    const float* Wq = (const float*)d_in[1];
    const float* Wk = (const float*)d_in[2];
    const float* Wv = (const float*)d_in[3];
    const float* Wo = (const float*)d_in[4];
    const float* bo = (const float*)d_in[5];
    float* out = (float*)d_out;

    // workspace: 143,257,600 B (~136.6 MiB)
    const size_t NE0 = (size_t)NBH * SEQL * 64;      // 8,388,608
    const size_t NEP = (size_t)NBH * PBH_POOL * 64;  // 8,323,072
    bfu* qb   = (bfu*)d_ws;            // q bf16; later y0/attn
    bfu* Wt   = qb + NE0;              // 4 transposed weights
    bfu* Qb   = Wt + 4 * 1048576;
    bfu* Kb   = Qb + NE0;
    bfu* Vb   = Kb + NE0;              // row-major V; reused as Vtp after transpose
    bfu* Vt0  = Vb + NE0;              // d-major level-0 V
    bfu* Qp   = Vt0 + NE0;
    bfu* Kp   = Qp + NEP;
    bfu* ylev = Kp + NEP;
    float* Alev = (float*)(ylev + NEP);              // 32*4064
    float* A0   = Alev + (size_t)NBH * PBH_POOL;     // 32*4096
    bfu* Vtp  = Vb;                    // overlay (Vb dead after transpose_v)

    cvt_q<<<8192, 256, 0, stream>>>(q, qb);
    transpose_cvt<<<dim3(32, 32, 4), 256, 0, stream>>>(Wq, Wk, Wv, Wo, Wt);

    gemm_mfma<0><<<dim3(24, 64), 256, 0, stream>>>(
        qb, Wt, Qb, Kb, Vb, nullptr, nullptr);

    transpose_v<<<dim3(64, NBH), 256, 0, stream>>>(Vb, Vt0);

    for (int lvl = 1; lvl < 8; ++lvl) {
        int Ld = 4096 >> lvl;
        int srcPerBH = (lvl == 1) ? SEQL : PBH_POOL;
        int srcRow0  = (lvl == 1) ? 0 : (4096 - (8192 >> (lvl - 1)));
        int dstRow0  = 4096 - (8192 >> lvl);
        const bfu* sq  = (lvl == 1) ? Qb : Qp;
        const bfu* sk  = (lvl == 1) ? Kb : Kp;
        const bfu* svt = (lvl == 1) ? Vt0 : Vtp;
        int svtCols    = (lvl == 1) ? SEQL : PBH_POOL;
        int nblk = (NBH * Ld * 32) / 256;
        pool2x<<<nblk, 256, 0, stream>>>(sq, sk, svt, Qp, Kp, Vtp,
                                         srcPerBH, srcRow0, dstRow0, Ld, svtCols);
    }

    pair_attn<<<dim3(255, NBH), 64, 0, stream>>>(
        Qb, Kb, Vt0, Qp, Kp, Vtp, qb /*y0*/, A0, ylev, Alev);

    gather_norm<<<32768, 256, 0, stream>>>(ylev, Alev, A0, qb);

    gemm_mfma<1><<<dim3(8, 64), 256, 0, stream>>>(
        qb, Wt + 3 * 1048576, nullptr, nullptr, nullptr, out, bo);
}

// Round 5
// 260.594 us; speedup vs baseline: 4.4334x; 1.1086x over previous
//
#include <hip/hip_runtime.h>
#include <cstddef>
#include <cstdint>

#define NHEADS 16
#define DHEAD  64
#define SEQL   4096
#define NBH    32            // batch*heads
#define PBH_POOL 4064        // pooled rows per BH (levels 1..7)

typedef unsigned short bfu;
typedef unsigned int u32;
typedef __attribute__((ext_vector_type(4)))  float f32x4;
typedef __attribute__((ext_vector_type(16))) float f32x16;
typedef __attribute__((ext_vector_type(8)))  short bf16x8;

__device__ inline float b2f(bfu b) { return __uint_as_float(((unsigned)b) << 16); }
__device__ inline bfu f2b(float f) {
    unsigned u = __float_as_uint(f);
    unsigned r = 0x7FFFu + ((u >> 16) & 1u);
    return (bfu)((u + r) >> 16);
}
__device__ inline u32 pk2(float a, float b) {
    return (u32)f2b(a) | ((u32)f2b(b) << 16);
}
__device__ inline bf16x8 mk8(u32 a, u32 b, u32 c, u32 d) {
    union { u32 u[4]; bf16x8 v; } x;
    x.u[0] = a; x.u[1] = b; x.u[2] = c; x.u[3] = d;
    return x.v;
}

// ---------------------------------------------------------------------------
// prep: blocks 0..8191 convert q fp32->bf16; blocks 8192..12287 transpose+cvt
// the 4 weights (1024x1024) -> Wt[widx][n][k] bf16.
// ---------------------------------------------------------------------------
__global__ __launch_bounds__(256) void prep(
    const float* __restrict__ q,
    const float* __restrict__ W0, const float* __restrict__ W1,
    const float* __restrict__ W2, const float* __restrict__ W3,
    bfu* __restrict__ qb, bfu* __restrict__ Wt)
{
    const int bid = blockIdx.x;
    if (bid < 8192) {
        size_t g = (size_t)bid * 256 + threadIdx.x;
        float4 v = *reinterpret_cast<const float4*>(&q[g * 4]);
        ushort4 s;
        s.x = f2b(v.x); s.y = f2b(v.y); s.z = f2b(v.z); s.w = f2b(v.w);
        *reinterpret_cast<ushort4*>(&qb[g * 4]) = s;
    } else {
        __shared__ float tl[32][33];
        const int b2 = bid - 8192;
        const int widx = b2 >> 10;
        const int tile = b2 & 1023;
        const float* src = (widx == 0) ? W0 : (widx == 1) ? W1 : (widx == 2) ? W2 : W3;
        bfu* dst = Wt + (size_t)widx * 1048576;
        const int n0 = (tile & 31) * 32, k0 = (tile >> 5) * 32;
        const int tx = threadIdx.x & 31, ty = threadIdx.x >> 5;
        #pragma unroll
        for (int i = 0; i < 4; ++i)
            tl[ty + 8 * i][tx] = src[(size_t)(k0 + ty + 8 * i) * 1024 + n0 + tx];
        __syncthreads();
        #pragma unroll
        for (int i = 0; i < 4; ++i)
            dst[(size_t)(n0 + ty + 8 * i) * 1024 + k0 + tx] = f2b(tl[tx][ty + 8 * i]);
    }
}

// ---------------------------------------------------------------------------
// bf16 MFMA GEMM, K=1024, 128x128 tile, 4 waves, 4x4x(16x16x32) frags/wave.
// global_load_lds width=16, linear LDS dest, swizzle on the GLOBAL source.
// MODE 0: N=3072 fused QKV. Q,K -> bf16 head-split [B,H,L,DH]; V (wsel==2)
//         written DIRECTLY d-major into Vt0[bh][d][l] (fused transpose).
// MODE 1: N=1024 -> fp32 row-major + bias.
// ---------------------------------------------------------------------------
template<int MODE>
__global__ __launch_bounds__(256) void gemm_mfma(
    const bfu* __restrict__ A, const bfu* __restrict__ Bt,
    bfu* __restrict__ O0, bfu* __restrict__ O1, bfu* __restrict__ O2,
    float* __restrict__ Ofp, const float* __restrict__ bias)
{
    __shared__ bfu As[128 * 32];
    __shared__ bfu Bs[128 * 32];
    const int tid = threadIdx.x;
    const int lane = tid & 63;
    const int wv = tid >> 6;
    const int wr = wv >> 1, wc = wv & 1;
    const int m0 = blockIdx.y * 128, n0 = blockIdx.x * 128;
    const int rlo = lane & 15, khi = lane >> 4;

    f32x4 acc[4][4];
    #pragma unroll
    for (int i = 0; i < 4; ++i)
        #pragma unroll
        for (int j = 0; j < 4; ++j)
            #pragma unroll
            for (int e = 0; e < 4; ++e) acc[i][j][e] = 0.f;

    for (int kt = 0; kt < 1024; kt += 32) {
        #pragma unroll
        for (int r = 0; r < 2; ++r) {
            int o = (r * 256 + tid) * 16;        // linear byte in 8192-B tile
            int row = o >> 6;                    // 64 B per row (32 bf16)
            int slot = (o >> 4) & 3;
            int sg = slot ^ ((row >> 1) & 3);    // pre-swizzled SOURCE slot
            __builtin_amdgcn_global_load_lds(
                (const __attribute__((address_space(1))) u32*)
                    &A[(size_t)(m0 + row) * 1024 + kt + sg * 8],
                (__attribute__((address_space(3))) u32*)
                    (reinterpret_cast<char*>(As) + o), 16, 0, 0);
            __builtin_amdgcn_global_load_lds(
                (const __attribute__((address_space(1))) u32*)
                    &Bt[(size_t)(n0 + row) * 1024 + kt + sg * 8],
                (__attribute__((address_space(3))) u32*)
                    (reinterpret_cast<char*>(Bs) + o), 16, 0, 0);
        }
        __syncthreads();
        bf16x8 af[4], bf_[4];
        #pragma unroll
        for (int mf = 0; mf < 4; ++mf) {
            int row = wr * 64 + mf * 16 + rlo;
            af[mf] = *reinterpret_cast<const bf16x8*>(
                reinterpret_cast<char*>(As) + row * 64 + ((khi ^ ((row >> 1) & 3)) << 4));
        }
        #pragma unroll
        for (int nf = 0; nf < 4; ++nf) {
            int row = wc * 64 + nf * 16 + rlo;
            bf_[nf] = *reinterpret_cast<const bf16x8*>(
                reinterpret_cast<char*>(Bs) + row * 64 + ((khi ^ ((row >> 1) & 3)) << 4));
        }
        #pragma unroll
        for (int mf = 0; mf < 4; ++mf)
            #pragma unroll
            for (int nf = 0; nf < 4; ++nf)
                acc[mf][nf] = __builtin_amdgcn_mfma_f32_16x16x32_bf16(
                    af[mf], bf_[nf], acc[mf][nf], 0, 0, 0);
        __syncthreads();
    }

    if (MODE == 0) {
        #pragma unroll
        for (int mf = 0; mf < 4; ++mf) {
            int l0m = m0 + wr * 64 + mf * 16 + khi * 4;   // 4-aligned, same b for rr group
            int b = l0m >> 12, l0 = l0m & 4095;
            #pragma unroll
            for (int nf = 0; nf < 4; ++nf) {
                int np = n0 + wc * 64 + nf * 16 + rlo;
                int wsel = np >> 10, n = np & 1023;
                int h = n >> 6, d = n & 63;
                if (wsel == 2) {
                    // fused transpose: Vt0[bh][d][l0..l0+3]
                    ushort4 s4;
                    s4.x = f2b(acc[mf][nf][0]); s4.y = f2b(acc[mf][nf][1]);
                    s4.z = f2b(acc[mf][nf][2]); s4.w = f2b(acc[mf][nf][3]);
                    *reinterpret_cast<ushort4*>(
                        &O2[((size_t)(b * NHEADS + h) * 64 + d) * SEQL + l0]) = s4;
                } else {
                    bfu* O = (wsel == 0) ? O0 : O1;
                    #pragma unroll
                    for (int rr = 0; rr < 4; ++rr)
                        O[(((size_t)(b * NHEADS + h)) * SEQL + l0 + rr) * DHEAD + d]
                            = f2b(acc[mf][nf][rr]);
                }
            }
        }
    } else {
        #pragma unroll
        for (int mf = 0; mf < 4; ++mf) {
            #pragma unroll
            for (int nf = 0; nf < 4; ++nf) {
                int np = n0 + wc * 64 + nf * 16 + rlo;
                float bb = bias[np];
                #pragma unroll
                for (int rr = 0; rr < 4; ++rr) {
                    int m = m0 + wr * 64 + mf * 16 + khi * 4 + rr;
                    Ofp[(size_t)m * 1024 + np] = acc[mf][nf][rr] + bb;
                }
            }
        }
    }
}

// ---------------------------------------------------------------------------
// pool_all: ALL 7 levels in one launch. 128 level-0 rows are self-contained
// for levels 1..7. Chain levels in fp32 LDS ping-pong (ref-accurate).
// blocks 0..2047: q/k  (tensor = bid>>10; bh = (bid&1023)>>5; seg = bid&31)
// blocks 2048..3071: v in d-major layout (pool along l within each d-row)
// ---------------------------------------------------------------------------
__global__ __launch_bounds__(256) void pool_all(
    const bfu* __restrict__ Qb, const bfu* __restrict__ Kb, const bfu* __restrict__ Vt0,
    bfu* __restrict__ Qp, bfu* __restrict__ Kp, bfu* __restrict__ Vtp)
{
    __shared__ bfu stg[8192];      // 16 KB: [128][64] (A) or [64][128] (B)
    __shared__ float buf0[4096];   // 16 KB fp32 ping
    __shared__ float buf1[4096];   // 16 KB fp32 pong
    const int bid = blockIdx.x;
    const int t = threadIdx.x;

    if (bid < 2048) {
        // ------- part A: q or k, row-major [l][d] -------
        const int tensor = bid >> 10;
        const int bh = (bid & 1023) >> 5, seg = bid & 31;
        const bfu* src = (tensor ? Kb : Qb) + ((size_t)bh * SEQL + seg * 128) * 64;
        bfu* dst = (tensor ? Kp : Qp) + (size_t)bh * PBH_POOL * 64;
        #pragma unroll
        for (int it = 0; it < 4; ++it) {
            int tt = it * 256 + t;             // 16B chunk: row=tt>>3, c8=tt&7
            *reinterpret_cast<uint4*>(&stg[(tt >> 3) * 64 + (tt & 7) * 8]) =
                *reinterpret_cast<const uint4*>(&src[(size_t)(tt >> 3) * 64 + (tt & 7) * 8]);
        }
        __syncthreads();
        // level 1: 64 rows x 64 d
        {
            int d = t & 63;
            #pragma unroll
            for (int i = 0; i < 16; ++i) {
                int r = (t >> 6) + 4 * i;
                float v = (b2f(stg[(2 * r) * 64 + d]) + b2f(stg[(2 * r + 1) * 64 + d])) * 0.5f;
                buf0[r * 64 + d] = v;
                dst[(size_t)(seg * 64 + r) * 64 + d] = f2b(v);   // dstRow0(1)=0
            }
        }
        __syncthreads();
        int nr = 32, dstRow0 = 2048;
        float* cur = buf0; float* nxt = buf1;
        for (int lvl = 2; lvl <= 7; ++lvl) {
            int elems = nr * 64;
            for (int i = t; i < elems; i += 256) {
                int r = i >> 6, dd = i & 63;
                float v = (cur[(2 * r) * 64 + dd] + cur[(2 * r + 1) * 64 + dd]) * 0.5f;
                nxt[r * 64 + dd] = v;
                dst[(size_t)(dstRow0 + seg * nr + r) * 64 + dd] = f2b(v);
            }
            __syncthreads();
            float* tmp = cur; cur = nxt; nxt = tmp;
            dstRow0 += 4096 >> lvl;
            nr >>= 1;
        }
    } else {
        // ------- part B: v, d-major [d][l] -------
        const int b2 = bid - 2048;
        const int bh = b2 >> 5, seg = b2 & 31;
        const bfu* src = Vt0 + (size_t)bh * 64 * SEQL + seg * 128;
        bfu* dst = Vtp + (size_t)bh * 64 * PBH_POOL;
        #pragma unroll
        for (int it = 0; it < 4; ++it) {
            int tt = it * 256 + t;             // 16B chunk: row=tt>>4, c8=tt&15
            *reinterpret_cast<uint4*>(&stg[(tt >> 4) * 128 + (tt & 15) * 8]) =
                *reinterpret_cast<const uint4*>(&src[(size_t)(tt >> 4) * SEQL + (tt & 15) * 8]);
        }
        __syncthreads();
        // level 1: 64 d-rows x 64 cols, SUM
        for (int i = t; i < 4096; i += 256) {
            int dd = i >> 6, c = i & 63;
            float v = b2f(stg[dd * 128 + 2 * c]) + b2f(stg[dd * 128 + 2 * c + 1]);
            buf0[dd * 64 + c] = v;
            dst[(size_t)dd * PBH_POOL + seg * 64 + c] = f2b(v);
        }
        __syncthreads();
        int nc = 32, lg = 5, dstRow0 = 2048;
        float* cur = buf0; float* nxt = buf1;
        for (int lvl = 2; lvl <= 7; ++lvl) {
            int elems = 64 * nc;
            for (int i = t; i < elems; i += 256) {
                int dd = i >> lg, c = i & (nc - 1);
                float v = cur[dd * 64 + 2 * c] + cur[dd * 64 + 2 * c + 1];
                nxt[dd * 64 + c] = v;
                dst[(size_t)dd * PBH_POOL + dstRow0 + seg * nc + c] = f2b(v);
            }
            __syncthreads();
            float* tmp = cur; cur = nxt; nxt = tmp;
            dstRow0 += 4096 >> lvl;
            nc >>= 1; --lg;
        }
    }
}

// ---------------------------------------------------------------------------
// pair_attn, 4 independent waves per block. One wave per (bh, block-pair).
// S^T = K.Q^T via mfma_32x32x16; in-register softmax; PV with d-major V.
// ---------------------------------------------------------------------------
__global__ __launch_bounds__(256) void pair_attn(
    const bfu* __restrict__ Q0, const bfu* __restrict__ K0, const bfu* __restrict__ Vt0,
    const bfu* __restrict__ Qp, const bfu* __restrict__ Kp, const bfu* __restrict__ Vtp,
    bfu* __restrict__ y0, float* __restrict__ A0,
    bfu* __restrict__ ylev, float* __restrict__ Alev)
{
    const int bh = blockIdx.y;
    const int slot = blockIdx.x * 4 + (threadIdx.x >> 6);
    if (slot >= 255) return;
    int s = slot, lvl = 0, cnt = 128;
    while (s >= cnt) { s -= cnt; cnt >>= 1; ++lvl; }
    const bfu *Q, *K, *Vt; int perbh, vcols, loff;
    if (lvl == 0) { Q = Q0; K = K0; Vt = Vt0; perbh = SEQL; vcols = SEQL; loff = 0; }
    else { Q = Qp; K = Kp; Vt = Vtp; perbh = PBH_POOL; vcols = PBH_POOL; loff = 4096 - (8192 >> lvl); }
    const int rbase = loff + s * 32;
    const int t = threadIdx.x & 63, q31 = t & 31, hl = t >> 5;

    const bfu* Krow = K + ((size_t)bh * perbh + rbase + q31) * 64 + hl * 8;
    const bfu* Qrow = Q + ((size_t)bh * perbh + rbase + q31) * 64 + hl * 8;

    f32x16 S;
    #pragma unroll
    for (int e = 0; e < 16; ++e) S[e] = 0.f;
    #pragma unroll
    for (int db = 0; db < 4; ++db) {
        bf16x8 ka = *reinterpret_cast<const bf16x8*>(Krow + db * 16);
        bf16x8 qa = *reinterpret_cast<const bf16x8*>(Qrow + db * 16);
        S = __builtin_amdgcn_mfma_f32_32x32x16_bf16(ka, qa, S, 0, 0, 0);
    }

    float p[16];
    #pragma unroll
    for (int r = 0; r < 16; ++r) p[r] = S[r] * 0.125f;
    float mlo = p[0], mhi = p[8];
    #pragma unroll
    for (int r = 1; r < 8; ++r) { mlo = fmaxf(mlo, p[r]); mhi = fmaxf(mhi, p[r + 8]); }
    mlo = fmaxf(mlo, __shfl_xor(mlo, 32));
    mhi = fmaxf(mhi, __shfl_xor(mhi, 32));
    #pragma unroll
    for (int r = 0; r < 8; ++r) {
        p[r]     = __expf(p[r]     - mlo);
        p[r + 8] = __expf(p[r + 8] - mhi);
    }
    if (lvl > 0) {
        #pragma unroll
        for (int r = 0; r < 8; ++r) {
            if (q31 < 16) p[r] = 0.f; else p[r + 8] = 0.f;
        }
    }
    float alo = 0.f, ahi = 0.f;
    #pragma unroll
    for (int r = 0; r < 8; ++r) { alo += p[r]; ahi += p[r + 8]; }
    alo += __shfl_xor(alo, 32);
    ahi += __shfl_xor(ahi, 32);
    const float Asum = alo + ahi;

    bf16x8 Pop[2];
    #pragma unroll
    for (int m = 0; m < 2; ++m) {
        u32 a0 = pk2(p[8 * m + 0], p[8 * m + 1]);
        u32 a1 = pk2(p[8 * m + 2], p[8 * m + 3]);
        u32 b0 = pk2(p[8 * m + 4], p[8 * m + 5]);
        u32 b1 = pk2(p[8 * m + 6], p[8 * m + 7]);
        u32 pa0 = __shfl_xor(a0, 32), pa1 = __shfl_xor(a1, 32);
        u32 pb0 = __shfl_xor(b0, 32), pb1 = __shfl_xor(b1, 32);
        Pop[m] = (hl == 0) ? mk8(a0, a1, pa0, pa1) : mk8(pb0, pb1, b0, b1);
    }

    const bfu* Vbase = Vt + (size_t)bh * 64 * vcols + rbase + hl * 8;
    f32x16 y[2];
    #pragma unroll
    for (int tt = 0; tt < 2; ++tt) {
        #pragma unroll
        for (int e = 0; e < 16; ++e) y[tt][e] = 0.f;
        #pragma unroll
        for (int m = 0; m < 2; ++m) {
            bf16x8 va = *reinterpret_cast<const bf16x8*>(
                Vbase + (size_t)(tt * 32 + q31) * vcols + m * 16);
            y[tt] = __builtin_amdgcn_mfma_f32_32x32x16_bf16(va, Pop[m], y[tt], 0, 0, 0);
        }
    }

    if (lvl == 0) {
        const int b = bh >> 4, h = bh & 15;
        bfu* orow = y0 + ((size_t)(b * SEQL + rbase + q31)) * 1024 + h * 64;
        #pragma unroll
        for (int tt = 0; tt < 2; ++tt)
            #pragma unroll
            for (int g = 0; g < 4; ++g) {
                int d0 = tt * 32 + g * 8 + hl * 4;
                ushort4 s4;
                s4.x = f2b(y[tt][4 * g + 0]); s4.y = f2b(y[tt][4 * g + 1]);
                s4.z = f2b(y[tt][4 * g + 2]); s4.w = f2b(y[tt][4 * g + 3]);
                *reinterpret_cast<ushort4*>(orow + d0) = s4;
            }
        if (hl == 0) A0[(size_t)bh * SEQL + rbase + q31] = Asum;
    } else {
        bfu* orow = ylev + ((size_t)bh * PBH_POOL + rbase + q31) * 64;
        #pragma unroll
        for (int tt = 0; tt < 2; ++tt)
            #pragma unroll
            for (int g = 0; g < 4; ++g) {
                int d0 = tt * 32 + g * 8 + hl * 4;
                ushort4 s4;
                s4.x = f2b(y[tt][4 * g + 0]); s4.y = f2b(y[tt][4 * g + 1]);
                s4.z = f2b(y[tt][4 * g + 2]); s4.w = f2b(y[tt][4 * g + 3]);
                *reinterpret_cast<ushort4*>(orow + d0) = s4;
            }
        if (hl == 0) Alev[(size_t)bh * PBH_POOL + rbase + q31] = Asum;
    }
}

// ---------------------------------------------------------------------------
// In-place: attn = (y0 + sum_levels ylev) / (A0 + sum Alev + eps), bf16.
// 4 d-elements per thread (A-sum loads amortized x4).
// ---------------------------------------------------------------------------
__global__ __launch_bounds__(256) void gather_norm(
    const bfu* __restrict__ ylev, const float* __restrict__ Alev,
    const float* __restrict__ A0, bfu* __restrict__ y0)
{
    size_t idx = ((size_t)blockIdx.x * 256 + threadIdx.x) * 4;
    int d0 = (int)(idx & 63);
    int h = (int)((idx >> 6) & 15);
    int l = (int)((idx >> 10) & 4095);
    int b = (int)(idx >> 22);
    int bh = b * NHEADS + h;

    ushort4 y4 = *reinterpret_cast<const ushort4*>(&y0[idx]);
    float ys0 = b2f(y4.x), ys1 = b2f(y4.y), ys2 = b2f(y4.z), ys3 = b2f(y4.w);
    float as = A0[(size_t)bh * SEQL + l];
    #pragma unroll
    for (int lvl = 1; lvl <= 7; ++lvl) {
        int r = (4096 - (8192 >> lvl)) + (l >> lvl);
        ushort4 v4 = *reinterpret_cast<const ushort4*>(
            &ylev[((size_t)bh * PBH_POOL + r) * 64 + d0]);
        ys0 += b2f(v4.x); ys1 += b2f(v4.y); ys2 += b2f(v4.z); ys3 += b2f(v4.w);
        as += Alev[(size_t)bh * PBH_POOL + r];
    }
    float inv = 1.0f / (as + 1e-12f);
    ushort4 o;
    o.x = f2b(ys0 * inv); o.y = f2b(ys1 * inv); o.z = f2b(ys2 * inv); o.w = f2b(ys3 * inv);
    *reinterpret_cast<ushort4*>(&y0[idx]) = o;
}

// ---------------------------------------------------------------------------
extern "C" void kernel_launch(void* const* d_in, const int* in_sizes, int n_in,
                              void* d_out, int out_size, void* d_ws, size_t ws_size,
                              hipStream_t stream)
{
    const float* q  = (const float*)d_in[0];
    const float* Wq = (const float*)d_in[1];
    const float* Wk = (const float*)d_in[2];
    const float* Wv = (const float*)d_in[3];
    const float* Wo = (const float*)d_in[4];
    const float* bo = (const float*)d_in[5];
    float* out = (float*)d_out;

    // workspace: ~143.1 MiB
    const size_t NE0 = (size_t)NBH * SEQL * 64;      // 8,388,608
    const size_t NEP = (size_t)NBH * PBH_POOL * 64;  // 8,323,072
    bfu* qb   = (bfu*)d_ws;            // q bf16; later y0/attn
    bfu* Wt   = qb + NE0;              // 4 transposed weights
    bfu* Qb   = Wt + 4 * 1048576;
    bfu* Kb   = Qb + NE0;
    bfu* Vt0  = Kb + NE0;              // d-major level-0 V (written by GEMM)
    bfu* Qp   = Vt0 + NE0;
    bfu* Kp   = Qp + NEP;
    bfu* Vtp  = Kp + NEP;
    bfu* ylev = Vtp + NEP;
    float* Alev = (float*)(ylev + NEP);              // 32*4064
    float* A0   = Alev + (size_t)NBH * PBH_POOL;     // 32*4096

    prep<<<12288, 256, 0, stream>>>(q, Wq, Wk, Wv, Wo, qb, Wt);

    // fused QKV; V written directly transposed into Vt0
    gemm_mfma<0><<<dim3(24, 64), 256, 0, stream>>>(
        qb, Wt, Qb, Kb, Vt0, nullptr, nullptr);

    pool_all<<<3072, 256, 0, stream>>>(Qb, Kb, Vt0, Qp, Kp, Vtp);

    pair_attn<<<dim3(64, NBH), 256, 0, stream>>>(
        Qb, Kb, Vt0, Qp, Kp, Vtp, qb /*y0*/, A0, ylev, Alev);

    gather_norm<<<8192, 256, 0, stream>>>(ylev, Alev, A0, qb);

    gemm_mfma<1><<<dim3(8, 64), 256, 0, stream>>>(
        qb, Wt + 3 * 1048576, nullptr, nullptr, nullptr, out, bo);
}

// Round 7
// 251.090 us; speedup vs baseline: 4.6012x; 1.0378x over previous
//
#include <hip/hip_runtime.h>
#include <cstddef>
#include <cstdint>

#define NHEADS 16
#define DHEAD  64
#define SEQL   4096
#define NBH    32            // batch*heads
#define PBH_POOL 4064        // pooled rows per BH (levels 1..7)

typedef unsigned short bfu;
typedef unsigned int u32;
typedef __attribute__((ext_vector_type(4)))  float f32x4;
typedef __attribute__((ext_vector_type(16))) float f32x16;
typedef __attribute__((ext_vector_type(8)))  short bf16x8;

__device__ inline float b2f(bfu b) { return __uint_as_float(((unsigned)b) << 16); }
__device__ inline bfu f2b(float f) {
    unsigned u = __float_as_uint(f);
    unsigned r = 0x7FFFu + ((u >> 16) & 1u);
    return (bfu)((u + r) >> 16);
}
__device__ inline u32 pk2(float a, float b) {
    return (u32)f2b(a) | ((u32)f2b(b) << 16);
}
__device__ inline bf16x8 mk8(u32 a, u32 b, u32 c, u32 d) {
    union { u32 u[4]; bf16x8 v; } x;
    x.u[0] = a; x.u[1] = b; x.u[2] = c; x.u[3] = d;
    return x.v;
}

// ---------------------------------------------------------------------------
// prep: blocks 0..8191 convert q fp32->bf16; blocks 8192..12287 transpose+cvt
// the 4 weights (1024x1024) -> Wt[widx][n][k] bf16.
// ---------------------------------------------------------------------------
__global__ __launch_bounds__(256) void prep(
    const float* __restrict__ q,
    const float* __restrict__ W0, const float* __restrict__ W1,
    const float* __restrict__ W2, const float* __restrict__ W3,
    bfu* __restrict__ qb, bfu* __restrict__ Wt)
{
    const int bid = blockIdx.x;
    if (bid < 8192) {
        size_t g = (size_t)bid * 256 + threadIdx.x;
        float4 v = *reinterpret_cast<const float4*>(&q[g * 4]);
        ushort4 s;
        s.x = f2b(v.x); s.y = f2b(v.y); s.z = f2b(v.z); s.w = f2b(v.w);
        *reinterpret_cast<ushort4*>(&qb[g * 4]) = s;
    } else {
        __shared__ float tl[32][33];
        const int b2 = bid - 8192;
        const int widx = b2 >> 10;
        const int tile = b2 & 1023;
        const float* src = (widx == 0) ? W0 : (widx == 1) ? W1 : (widx == 2) ? W2 : W3;
        bfu* dst = Wt + (size_t)widx * 1048576;
        const int n0 = (tile & 31) * 32, k0 = (tile >> 5) * 32;
        const int tx = threadIdx.x & 31, ty = threadIdx.x >> 5;
        #pragma unroll
        for (int i = 0; i < 4; ++i)
            tl[ty + 8 * i][tx] = src[(size_t)(k0 + ty + 8 * i) * 1024 + n0 + tx];
        __syncthreads();
        #pragma unroll
        for (int i = 0; i < 4; ++i)
            dst[(size_t)(n0 + ty + 8 * i) * 1024 + k0 + tx] = f2b(tl[tx][ty + 8 * i]);
    }
}

// ---------------------------------------------------------------------------
// bf16 MFMA GEMM, K=1024, 128x128 tile, 4 waves, 4x4x(16x16x32) frags/wave.
// 1D grid + bijective 4x2 XCD partition: xcd (bid&7) split as (m-group: xcd>>1,
// n-group: xcd&1); within-XCD index sweeps m fast so A-panels stay in L2.
// global_load_lds width=16, linear LDS dest, swizzle on the GLOBAL source.
// MODE 0: N=3072 fused QKV. Q,K -> bf16 head-split [B,H,L,DH]; V (wsel==2)
//         written DIRECTLY d-major into Vt0[bh][d][l] (fused transpose).
// MODE 1: N=1024 -> fp32 row-major + bias.
// ---------------------------------------------------------------------------
template<int MODE>
__global__ __launch_bounds__(256) void gemm_mfma(
    const bfu* __restrict__ A, const bfu* __restrict__ Bt,
    bfu* __restrict__ O0, bfu* __restrict__ O1, bfu* __restrict__ O2,
    float* __restrict__ Ofp, const float* __restrict__ bias, int nPerX)
{
    __shared__ bfu As[128 * 32];
    __shared__ bfu Bs[128 * 32];
    const int tid = threadIdx.x;
    const int lane = tid & 63;
    const int wv = tid >> 6;
    const int wr = wv >> 1, wc = wv & 1;
    // 4x2 XCD partition: 4 m-groups x 2 n-groups; m sweeps fast within XCD
    const int xcd = blockIdx.x & 7;
    const int i = blockIdx.x >> 3;
    const int m0 = (((xcd >> 1) << 4) + (i & 15)) * 128;
    const int n0 = ((xcd & 1) * nPerX + (i >> 4)) * 128;
    const int rlo = lane & 15, khi = lane >> 4;

    f32x4 acc[4][4];
    #pragma unroll
    for (int i2 = 0; i2 < 4; ++i2)
        #pragma unroll
        for (int j = 0; j < 4; ++j)
            #pragma unroll
            for (int e = 0; e < 4; ++e) acc[i2][j][e] = 0.f;

    for (int kt = 0; kt < 1024; kt += 32) {
        #pragma unroll
        for (int r = 0; r < 2; ++r) {
            int o = (r * 256 + tid) * 16;        // linear byte in 8192-B tile
            int row = o >> 6;                    // 64 B per row (32 bf16)
            int slot = (o >> 4) & 3;
            int sg = slot ^ ((row >> 1) & 3);    // pre-swizzled SOURCE slot
            __builtin_amdgcn_global_load_lds(
                (const __attribute__((address_space(1))) u32*)
                    &A[(size_t)(m0 + row) * 1024 + kt + sg * 8],
                (__attribute__((address_space(3))) u32*)
                    (reinterpret_cast<char*>(As) + o), 16, 0, 0);
            __builtin_amdgcn_global_load_lds(
                (const __attribute__((address_space(1))) u32*)
                    &Bt[(size_t)(n0 + row) * 1024 + kt + sg * 8],
                (__attribute__((address_space(3))) u32*)
                    (reinterpret_cast<char*>(Bs) + o), 16, 0, 0);
        }
        __syncthreads();
        bf16x8 af[4], bf_[4];
        #pragma unroll
        for (int mf = 0; mf < 4; ++mf) {
            int row = wr * 64 + mf * 16 + rlo;
            af[mf] = *reinterpret_cast<const bf16x8*>(
                reinterpret_cast<char*>(As) + row * 64 + ((khi ^ ((row >> 1) & 3)) << 4));
        }
        #pragma unroll
        for (int nf = 0; nf < 4; ++nf) {
            int row = wc * 64 + nf * 16 + rlo;
            bf_[nf] = *reinterpret_cast<const bf16x8*>(
                reinterpret_cast<char*>(Bs) + row * 64 + ((khi ^ ((row >> 1) & 3)) << 4));
        }
        #pragma unroll
        for (int mf = 0; mf < 4; ++mf)
            #pragma unroll
            for (int nf = 0; nf < 4; ++nf)
                acc[mf][nf] = __builtin_amdgcn_mfma_f32_16x16x32_bf16(
                    af[mf], bf_[nf], acc[mf][nf], 0, 0, 0);
        __syncthreads();
    }

    if (MODE == 0) {
        #pragma unroll
        for (int mf = 0; mf < 4; ++mf) {
            int l0m = m0 + wr * 64 + mf * 16 + khi * 4;   // 4-aligned, same b for rr group
            int b = l0m >> 12, l0 = l0m & 4095;
            #pragma unroll
            for (int nf = 0; nf < 4; ++nf) {
                int np = n0 + wc * 64 + nf * 16 + rlo;
                int wsel = np >> 10, n = np & 1023;
                int h = n >> 6, d = n & 63;
                if (wsel == 2) {
                    // fused transpose: Vt0[bh][d][l0..l0+3]
                    ushort4 s4;
                    s4.x = f2b(acc[mf][nf][0]); s4.y = f2b(acc[mf][nf][1]);
                    s4.z = f2b(acc[mf][nf][2]); s4.w = f2b(acc[mf][nf][3]);
                    *reinterpret_cast<ushort4*>(
                        &O2[((size_t)(b * NHEADS + h) * 64 + d) * SEQL + l0]) = s4;
                } else {
                    bfu* O = (wsel == 0) ? O0 : O1;
                    #pragma unroll
                    for (int rr = 0; rr < 4; ++rr)
                        O[(((size_t)(b * NHEADS + h)) * SEQL + l0 + rr) * DHEAD + d]
                            = f2b(acc[mf][nf][rr]);
                }
            }
        }
    } else {
        #pragma unroll
        for (int mf = 0; mf < 4; ++mf) {
            #pragma unroll
            for (int nf = 0; nf < 4; ++nf) {
                int np = n0 + wc * 64 + nf * 16 + rlo;
                float bb = bias[np];
                #pragma unroll
                for (int rr = 0; rr < 4; ++rr) {
                    int m = m0 + wr * 64 + mf * 16 + khi * 4 + rr;
                    Ofp[(size_t)m * 1024 + np] = acc[mf][nf][rr] + bb;
                }
            }
        }
    }
}

// ---------------------------------------------------------------------------
// pool_all: ALL 7 levels in one launch. 128 level-0 rows are self-contained
// for levels 1..7. Chain levels in fp32 LDS ping-pong (ref-accurate).
// blocks 0..2047: q/k  (tensor = bid>>10; bh = (bid&1023)>>5; seg = bid&31)
// blocks 2048..3071: v in d-major layout (pool along l within each d-row)
// ---------------------------------------------------------------------------
__global__ __launch_bounds__(256) void pool_all(
    const bfu* __restrict__ Qb, const bfu* __restrict__ Kb, const bfu* __restrict__ Vt0,
    bfu* __restrict__ Qp, bfu* __restrict__ Kp, bfu* __restrict__ Vtp)
{
    __shared__ bfu stg[8192];      // 16 KB: [128][64] (A) or [64][128] (B)
    __shared__ float buf0[4096];   // 16 KB fp32 ping
    __shared__ float buf1[4096];   // 16 KB fp32 pong
    const int bid = blockIdx.x;
    const int t = threadIdx.x;

    if (bid < 2048) {
        // ------- part A: q or k, row-major [l][d] -------
        const int tensor = bid >> 10;
        const int bh = (bid & 1023) >> 5, seg = bid & 31;
        const bfu* src = (tensor ? Kb : Qb) + ((size_t)bh * SEQL + seg * 128) * 64;
        bfu* dst = (tensor ? Kp : Qp) + (size_t)bh * PBH_POOL * 64;
        #pragma unroll
        for (int it = 0; it < 4; ++it) {
            int tt = it * 256 + t;             // 16B chunk: row=tt>>3, c8=tt&7
            *reinterpret_cast<uint4*>(&stg[(tt >> 3) * 64 + (tt & 7) * 8]) =
                *reinterpret_cast<const uint4*>(&src[(size_t)(tt >> 3) * 64 + (tt & 7) * 8]);
        }
        __syncthreads();
        // level 1: 64 rows x 64 d
        {
            int d = t & 63;
            #pragma unroll
            for (int i = 0; i < 16; ++i) {
                int r = (t >> 6) + 4 * i;
                float v = (b2f(stg[(2 * r) * 64 + d]) + b2f(stg[(2 * r + 1) * 64 + d])) * 0.5f;
                buf0[r * 64 + d] = v;
                dst[(size_t)(seg * 64 + r) * 64 + d] = f2b(v);   // dstRow0(1)=0
            }
        }
        __syncthreads();
        int nr = 32, dstRow0 = 2048;
        float* cur = buf0; float* nxt = buf1;
        for (int lvl = 2; lvl <= 7; ++lvl) {
            int elems = nr * 64;
            for (int i = t; i < elems; i += 256) {
                int r = i >> 6, dd = i & 63;
                float v = (cur[(2 * r) * 64 + dd] + cur[(2 * r + 1) * 64 + dd]) * 0.5f;
                nxt[r * 64 + dd] = v;
                dst[(size_t)(dstRow0 + seg * nr + r) * 64 + dd] = f2b(v);
            }
            __syncthreads();
            float* tmp = cur; cur = nxt; nxt = tmp;
            dstRow0 += 4096 >> lvl;
            nr >>= 1;
        }
    } else {
        // ------- part B: v, d-major [d][l] -------
        const int b2 = bid - 2048;
        const int bh = b2 >> 5, seg = b2 & 31;
        const bfu* src = Vt0 + (size_t)bh * 64 * SEQL + seg * 128;
        bfu* dst = Vtp + (size_t)bh * 64 * PBH_POOL;
        #pragma unroll
        for (int it = 0; it < 4; ++it) {
            int tt = it * 256 + t;             // 16B chunk: row=tt>>4, c8=tt&15
            *reinterpret_cast<uint4*>(&stg[(tt >> 4) * 128 + (tt & 15) * 8]) =
                *reinterpret_cast<const uint4*>(&src[(size_t)(tt >> 4) * SEQL + (tt & 15) * 8]);
        }
        __syncthreads();
        // level 1: 64 d-rows x 64 cols, SUM
        for (int i = t; i < 4096; i += 256) {
            int dd = i >> 6, c = i & 63;
            float v = b2f(stg[dd * 128 + 2 * c]) + b2f(stg[dd * 128 + 2 * c + 1]);
            buf0[dd * 64 + c] = v;
            dst[(size_t)dd * PBH_POOL + seg * 64 + c] = f2b(v);
        }
        __syncthreads();
        int nc = 32, lg = 5, dstRow0 = 2048;
        float* cur = buf0; float* nxt = buf1;
        for (int lvl = 2; lvl <= 7; ++lvl) {
            int elems = 64 * nc;
            for (int i = t; i < elems; i += 256) {
                int dd = i >> lg, c = i & (nc - 1);
                float v = cur[dd * 64 + 2 * c] + cur[dd * 64 + 2 * c + 1];
                nxt[dd * 64 + c] = v;
                dst[(size_t)dd * PBH_POOL + dstRow0 + seg * nc + c] = f2b(v);
            }
            __syncthreads();
            float* tmp = cur; cur = nxt; nxt = tmp;
            dstRow0 += 4096 >> lvl;
            nc >>= 1; --lg;
        }
    }
}

// ---------------------------------------------------------------------------
// pair_attn, 4 independent waves per block, one wave per (bh, block-pair).
// Direct global loads (r5 form — race-free). S^T = K.Q^T via mfma_32x32x16;
// in-register softmax; PV with d-major V.
// ---------------------------------------------------------------------------
__global__ __launch_bounds__(256) void pair_attn(
    const bfu* __restrict__ Q0, const bfu* __restrict__ K0, const bfu* __restrict__ Vt0,
    const bfu* __restrict__ Qp, const bfu* __restrict__ Kp, const bfu* __restrict__ Vtp,
    bfu* __restrict__ y0, float* __restrict__ A0,
    bfu* __restrict__ ylev, float* __restrict__ Alev)
{
    const int bh = blockIdx.y;
    const int slot = blockIdx.x * 4 + (threadIdx.x >> 6);
    if (slot >= 255) return;
    int s = slot, lvl = 0, cnt = 128;
    while (s >= cnt) { s -= cnt; cnt >>= 1; ++lvl; }
    const bfu *Q, *K, *Vt; int perbh, vcols, loff;
    if (lvl == 0) { Q = Q0; K = K0; Vt = Vt0; perbh = SEQL; vcols = SEQL; loff = 0; }
    else { Q = Qp; K = Kp; Vt = Vtp; perbh = PBH_POOL; vcols = PBH_POOL; loff = 4096 - (8192 >> lvl); }
    const int rbase = loff + s * 32;
    const int t = threadIdx.x & 63, q31 = t & 31, hl = t >> 5;

    const bfu* Krow = K + ((size_t)bh * perbh + rbase + q31) * 64 + hl * 8;
    const bfu* Qrow = Q + ((size_t)bh * perbh + rbase + q31) * 64 + hl * 8;

    // S^T = K.Q^T  (C: col=lane&31=q, row kk=(reg&3)+8*(reg>>2)+4*(lane>>5))
    f32x16 S;
    #pragma unroll
    for (int e = 0; e < 16; ++e) S[e] = 0.f;
    #pragma unroll
    for (int db = 0; db < 4; ++db) {
        bf16x8 ka = *reinterpret_cast<const bf16x8*>(Krow + db * 16);
        bf16x8 qa = *reinterpret_cast<const bf16x8*>(Qrow + db * 16);
        S = __builtin_amdgcn_mfma_f32_32x32x16_bf16(ka, qa, S, 0, 0, 0);
    }

    float p[16];
    #pragma unroll
    for (int r = 0; r < 16; ++r) p[r] = S[r] * 0.125f;
    float mlo = p[0], mhi = p[8];
    #pragma unroll
    for (int r = 1; r < 8; ++r) { mlo = fmaxf(mlo, p[r]); mhi = fmaxf(mhi, p[r + 8]); }
    mlo = fmaxf(mlo, __shfl_xor(mlo, 32));
    mhi = fmaxf(mhi, __shfl_xor(mhi, 32));
    #pragma unroll
    for (int r = 0; r < 8; ++r) {
        p[r]     = __expf(p[r]     - mlo);
        p[r + 8] = __expf(p[r + 8] - mhi);
    }
    if (lvl > 0) {
        #pragma unroll
        for (int r = 0; r < 8; ++r) {
            if (q31 < 16) p[r] = 0.f; else p[r + 8] = 0.f;
        }
    }
    float alo = 0.f, ahi = 0.f;
    #pragma unroll
    for (int r = 0; r < 8; ++r) { alo += p[r]; ahi += p[r + 8]; }
    alo += __shfl_xor(alo, 32);
    ahi += __shfl_xor(ahi, 32);
    const float Asum = alo + ahi;

    // pack P^T into MFMA B operands (lane: col=q, k = kk = 16m + hl*8 + e)
    bf16x8 Pop[2];
    #pragma unroll
    for (int m = 0; m < 2; ++m) {
        u32 a0 = pk2(p[8 * m + 0], p[8 * m + 1]);
        u32 a1 = pk2(p[8 * m + 2], p[8 * m + 3]);
        u32 b0 = pk2(p[8 * m + 4], p[8 * m + 5]);
        u32 b1 = pk2(p[8 * m + 6], p[8 * m + 7]);
        u32 pa0 = __shfl_xor(a0, 32), pa1 = __shfl_xor(a1, 32);
        u32 pb0 = __shfl_xor(b0, 32), pb1 = __shfl_xor(b1, 32);
        Pop[m] = (hl == 0) ? mk8(a0, a1, pa0, pa1) : mk8(pb0, pb1, b0, b1);
    }

    // y^T = V^T.P^T with V in d-major layout -> each lane owns one y row
    const bfu* Vbase = Vt + (size_t)bh * 64 * vcols + rbase + hl * 8;
    f32x16 y[2];
    #pragma unroll
    for (int tt = 0; tt < 2; ++tt) {
        #pragma unroll
        for (int e = 0; e < 16; ++e) y[tt][e] = 0.f;
        #pragma unroll
        for (int m = 0; m < 2; ++m) {
            bf16x8 va = *reinterpret_cast<const bf16x8*>(
                Vbase + (size_t)(tt * 32 + q31) * vcols + m * 16);
            y[tt] = __builtin_amdgcn_mfma_f32_32x32x16_bf16(va, Pop[m], y[tt], 0, 0, 0);
        }
    }

    if (lvl == 0) {
        const int b = bh >> 4, h = bh & 15;
        bfu* orow = y0 + ((size_t)(b * SEQL + rbase + q31)) * 1024 + h * 64;
        #pragma unroll
        for (int tt = 0; tt < 2; ++tt)
            #pragma unroll
            for (int g = 0; g < 4; ++g) {
                int d0 = tt * 32 + g * 8 + hl * 4;
                ushort4 s4;
                s4.x = f2b(y[tt][4 * g + 0]); s4.y = f2b(y[tt][4 * g + 1]);
                s4.z = f2b(y[tt][4 * g + 2]); s4.w = f2b(y[tt][4 * g + 3]);
                *reinterpret_cast<ushort4*>(orow + d0) = s4;
            }
        if (hl == 0) A0[(size_t)bh * SEQL + rbase + q31] = Asum;
    } else {
        bfu* orow = ylev + ((size_t)bh * PBH_POOL + rbase + q31) * 64;
        #pragma unroll
        for (int tt = 0; tt < 2; ++tt)
            #pragma unroll
            for (int g = 0; g < 4; ++g) {
                int d0 = tt * 32 + g * 8 + hl * 4;
                ushort4 s4;
                s4.x = f2b(y[tt][4 * g + 0]); s4.y = f2b(y[tt][4 * g + 1]);
                s4.z = f2b(y[tt][4 * g + 2]); s4.w = f2b(y[tt][4 * g + 3]);
                *reinterpret_cast<ushort4*>(orow + d0) = s4;
            }
        if (hl == 0) Alev[(size_t)bh * PBH_POOL + rbase + q31] = Asum;
    }
}

// ---------------------------------------------------------------------------
// In-place: attn = (y0 + sum_levels ylev) / (A0 + sum Alev + eps), bf16.
// 4 d-elements per thread (A-sum loads amortized x4).
// ---------------------------------------------------------------------------
__global__ __launch_bounds__(256) void gather_norm(
    const bfu* __restrict__ ylev, const float* __restrict__ Alev,
    const float* __restrict__ A0, bfu* __restrict__ y0)
{
    size_t idx = ((size_t)blockIdx.x * 256 + threadIdx.x) * 4;
    int d0 = (int)(idx & 63);
    int h = (int)((idx >> 6) & 15);
    int l = (int)((idx >> 10) & 4095);
    int b = (int)(idx >> 22);
    int bh = b * NHEADS + h;

    ushort4 y4 = *reinterpret_cast<const ushort4*>(&y0[idx]);
    float ys0 = b2f(y4.x), ys1 = b2f(y4.y), ys2 = b2f(y4.z), ys3 = b2f(y4.w);
    float as = A0[(size_t)bh * SEQL + l];
    #pragma unroll
    for (int lvl = 1; lvl <= 7; ++lvl) {
        int r = (4096 - (8192 >> lvl)) + (l >> lvl);
        ushort4 v4 = *reinterpret_cast<const ushort4*>(
            &ylev[((size_t)bh * PBH_POOL + r) * 64 + d0]);
        ys0 += b2f(v4.x); ys1 += b2f(v4.y); ys2 += b2f(v4.z); ys3 += b2f(v4.w);
        as += Alev[(size_t)bh * PBH_POOL + r];
    }
    float inv = 1.0f / (as + 1e-12f);
    ushort4 o;
    o.x = f2b(ys0 * inv); o.y = f2b(ys1 * inv); o.z = f2b(ys2 * inv); o.w = f2b(ys3 * inv);
    *reinterpret_cast<ushort4*>(&y0[idx]) = o;
}

// ---------------------------------------------------------------------------
extern "C" void kernel_launch(void* const* d_in, const int* in_sizes, int n_in,
                              void* d_out, int out_size, void* d_ws, size_t ws_size,
                              hipStream_t stream)
{
    const float* q  = (const float*)d_in[0];
    const float* Wq = (const float*)d_in[1];
    const float* Wk = (const float*)d_in[2];
    const float* Wv = (const float*)d_in[3];
    const float* Wo = (const float*)d_in[4];
    const float* bo = (const float*)d_in[5];
    float* out = (float*)d_out;

    // workspace: ~143.1 MiB
    const size_t NE0 = (size_t)NBH * SEQL * 64;      // 8,388,608
    const size_t NEP = (size_t)NBH * PBH_POOL * 64;  // 8,323,072
    bfu* qb   = (bfu*)d_ws;            // q bf16; later y0/attn
    bfu* Wt   = qb + NE0;              // 4 transposed weights
    bfu* Qb   = Wt + 4 * 1048576;
    bfu* Kb   = Qb + NE0;
    bfu* Vt0  = Kb + NE0;              // d-major level-0 V (written by GEMM)
    bfu* Qp   = Vt0 + NE0;
    bfu* Kp   = Qp + NEP;
    bfu* Vtp  = Kp + NEP;
    bfu* ylev = Vtp + NEP;
    float* Alev = (float*)(ylev + NEP);              // 32*4064
    float* A0   = Alev + (size_t)NBH * PBH_POOL;     // 32*4096

    prep<<<12288, 256, 0, stream>>>(q, Wq, Wk, Wv, Wo, qb, Wt);

    // fused QKV; V written directly transposed into Vt0. 1536 blocks, nPerX=12.
    gemm_mfma<0><<<1536, 256, 0, stream>>>(
        qb, Wt, Qb, Kb, Vt0, nullptr, nullptr, 12);

    pool_all<<<3072, 256, 0, stream>>>(Qb, Kb, Vt0, Qp, Kp, Vtp);

    pair_attn<<<dim3(64, NBH), 256, 0, stream>>>(
        Qb, Kb, Vt0, Qp, Kp, Vtp, qb /*y0*/, A0, ylev, Alev);

    gather_norm<<<8192, 256, 0, stream>>>(ylev, Alev, A0, qb);

    gemm_mfma<1><<<512, 256, 0, stream>>>(
        qb, Wt + 3 * 1048576, nullptr, nullptr, nullptr, out, bo, 4);
}

// Round 8
// 250.214 us; speedup vs baseline: 4.6173x; 1.0035x over previous
//
#include <hip/hip_runtime.h>
#include <cstddef>
#include <cstdint>

#define NHEADS 16
#define DHEAD  64
#define SEQL   4096
#define NBH    32            // batch*heads
#define PBH_POOL 4064        // pooled rows per BH (levels 1..7)

typedef unsigned short bfu;
typedef unsigned int u32;
typedef __attribute__((ext_vector_type(4)))  float f32x4;
typedef __attribute__((ext_vector_type(16))) float f32x16;
typedef __attribute__((ext_vector_type(8)))  short bf16x8;

__device__ inline float b2f(bfu b) { return __uint_as_float(((unsigned)b) << 16); }
__device__ inline bfu f2b(float f) {
    unsigned u = __float_as_uint(f);
    unsigned r = 0x7FFFu + ((u >> 16) & 1u);
    return (bfu)((u + r) >> 16);
}
__device__ inline u32 pk2(float a, float b) {
    return (u32)f2b(a) | ((u32)f2b(b) << 16);
}
__device__ inline bf16x8 mk8(u32 a, u32 b, u32 c, u32 d) {
    union { u32 u[4]; bf16x8 v; } x;
    x.u[0] = a; x.u[1] = b; x.u[2] = c; x.u[3] = d;
    return x.v;
}

// ---------------------------------------------------------------------------
// prep: blocks 0..8191 convert q fp32->bf16; blocks 8192..12287 transpose+cvt
// the 4 weights (1024x1024) -> Wt[widx][n][k] bf16.
// ---------------------------------------------------------------------------
__global__ __launch_bounds__(256) void prep(
    const float* __restrict__ q,
    const float* __restrict__ W0, const float* __restrict__ W1,
    const float* __restrict__ W2, const float* __restrict__ W3,
    bfu* __restrict__ qb, bfu* __restrict__ Wt)
{
    const int bid = blockIdx.x;
    if (bid < 8192) {
        size_t g = (size_t)bid * 256 + threadIdx.x;
        float4 v = *reinterpret_cast<const float4*>(&q[g * 4]);
        ushort4 s;
        s.x = f2b(v.x); s.y = f2b(v.y); s.z = f2b(v.z); s.w = f2b(v.w);
        *reinterpret_cast<ushort4*>(&qb[g * 4]) = s;
    } else {
        __shared__ float tl[32][33];
        const int b2 = bid - 8192;
        const int widx = b2 >> 10;
        const int tile = b2 & 1023;
        const float* src = (widx == 0) ? W0 : (widx == 1) ? W1 : (widx == 2) ? W2 : W3;
        bfu* dst = Wt + (size_t)widx * 1048576;
        const int n0 = (tile & 31) * 32, k0 = (tile >> 5) * 32;
        const int tx = threadIdx.x & 31, ty = threadIdx.x >> 5;
        #pragma unroll
        for (int i = 0; i < 4; ++i)
            tl[ty + 8 * i][tx] = src[(size_t)(k0 + ty + 8 * i) * 1024 + n0 + tx];
        __syncthreads();
        #pragma unroll
        for (int i = 0; i < 4; ++i)
            dst[(size_t)(n0 + ty + 8 * i) * 1024 + k0 + tx] = f2b(tl[tx][ty + 8 * i]);
    }
}

// ---------------------------------------------------------------------------
// bf16 MFMA GEMM, K=1024, 128x128 tile, BK=64 (32 MFMA per barrier period),
// 4 waves, 4x4 frags of 16x16x32 per wave, 2 K-subtiles per LDS buffer.
// LDS 128 rows x 128 B; XOR swizzle slot^=(row&7), applied to the GLOBAL
// source (linear LDS dest, rule 21); fragment reads use the same XOR.
// MODE 0: N=3072 fused QKV. Q,K -> bf16 head-split [B,H,L,DH]; V (wsel==2)
//         written DIRECTLY d-major into Vt0[bh][d][l] (fused transpose).
// MODE 1: N=1024 -> fp32 row-major + bias.
// ---------------------------------------------------------------------------
template<int MODE>
__global__ __launch_bounds__(256) void gemm_mfma(
    const bfu* __restrict__ A, const bfu* __restrict__ Bt,
    bfu* __restrict__ O0, bfu* __restrict__ O1, bfu* __restrict__ O2,
    float* __restrict__ Ofp, const float* __restrict__ bias)
{
    __shared__ bfu As[128 * 64];   // 16 KB
    __shared__ bfu Bs[128 * 64];   // 16 KB
    const int tid = threadIdx.x;
    const int lane = tid & 63;
    const int wv = tid >> 6;
    const int wr = wv >> 1, wc = wv & 1;
    const int m0 = blockIdx.y * 128, n0 = blockIdx.x * 128;
    const int rlo = lane & 15, khi = lane >> 4;

    f32x4 acc[4][4];
    #pragma unroll
    for (int i = 0; i < 4; ++i)
        #pragma unroll
        for (int j = 0; j < 4; ++j)
            #pragma unroll
            for (int e = 0; e < 4; ++e) acc[i][j][e] = 0.f;

    for (int kt = 0; kt < 1024; kt += 64) {
        #pragma unroll
        for (int r = 0; r < 4; ++r) {
            int o = (r * 256 + tid) * 16;        // linear byte in 16-KB tile
            int row = o >> 7;                    // 128 B per row (64 bf16)
            int slot = (o >> 4) & 7;             // 16-B slot within row
            int sg = slot ^ (row & 7);           // pre-swizzled SOURCE slot
            __builtin_amdgcn_global_load_lds(
                (const __attribute__((address_space(1))) u32*)
                    &A[(size_t)(m0 + row) * 1024 + kt + sg * 8],
                (__attribute__((address_space(3))) u32*)
                    (reinterpret_cast<char*>(As) + o), 16, 0, 0);
            __builtin_amdgcn_global_load_lds(
                (const __attribute__((address_space(1))) u32*)
                    &Bt[(size_t)(n0 + row) * 1024 + kt + sg * 8],
                (__attribute__((address_space(3))) u32*)
                    (reinterpret_cast<char*>(Bs) + o), 16, 0, 0);
        }
        __syncthreads();
        // fragment reads: global chunk g = kk*4 + khi of row -> phys slot g^(row&7)
        bf16x8 af[2][4], bf_[2][4];
        #pragma unroll
        for (int kk = 0; kk < 2; ++kk) {
            #pragma unroll
            for (int mf = 0; mf < 4; ++mf) {
                int row = wr * 64 + mf * 16 + rlo;
                af[kk][mf] = *reinterpret_cast<const bf16x8*>(
                    reinterpret_cast<char*>(As) + row * 128
                    + (((kk * 4 + khi) ^ (row & 7)) << 4));
            }
            #pragma unroll
            for (int nf = 0; nf < 4; ++nf) {
                int row = wc * 64 + nf * 16 + rlo;
                bf_[kk][nf] = *reinterpret_cast<const bf16x8*>(
                    reinterpret_cast<char*>(Bs) + row * 128
                    + (((kk * 4 + khi) ^ (row & 7)) << 4));
            }
        }
        #pragma unroll
        for (int mf = 0; mf < 4; ++mf)
            #pragma unroll
            for (int nf = 0; nf < 4; ++nf) {
                // kk=0 then kk=1 preserves the old (kt, kt+32) accumulation order
                acc[mf][nf] = __builtin_amdgcn_mfma_f32_16x16x32_bf16(
                    af[0][mf], bf_[0][nf], acc[mf][nf], 0, 0, 0);
                acc[mf][nf] = __builtin_amdgcn_mfma_f32_16x16x32_bf16(
                    af[1][mf], bf_[1][nf], acc[mf][nf], 0, 0, 0);
            }
        __syncthreads();
    }

    if (MODE == 0) {
        #pragma unroll
        for (int mf = 0; mf < 4; ++mf) {
            int l0m = m0 + wr * 64 + mf * 16 + khi * 4;   // 4-aligned, same b for rr group
            int b = l0m >> 12, l0 = l0m & 4095;
            #pragma unroll
            for (int nf = 0; nf < 4; ++nf) {
                int np = n0 + wc * 64 + nf * 16 + rlo;
                int wsel = np >> 10, n = np & 1023;
                int h = n >> 6, d = n & 63;
                if (wsel == 2) {
                    // fused transpose: Vt0[bh][d][l0..l0+3]
                    ushort4 s4;
                    s4.x = f2b(acc[mf][nf][0]); s4.y = f2b(acc[mf][nf][1]);
                    s4.z = f2b(acc[mf][nf][2]); s4.w = f2b(acc[mf][nf][3]);
                    *reinterpret_cast<ushort4*>(
                        &O2[((size_t)(b * NHEADS + h) * 64 + d) * SEQL + l0]) = s4;
                } else {
                    bfu* O = (wsel == 0) ? O0 : O1;
                    #pragma unroll
                    for (int rr = 0; rr < 4; ++rr)
                        O[(((size_t)(b * NHEADS + h)) * SEQL + l0 + rr) * DHEAD + d]
                            = f2b(acc[mf][nf][rr]);
                }
            }
        }
    } else {
        #pragma unroll
        for (int mf = 0; mf < 4; ++mf) {
            #pragma unroll
            for (int nf = 0; nf < 4; ++nf) {
                int np = n0 + wc * 64 + nf * 16 + rlo;
                float bb = bias[np];
                #pragma unroll
                for (int rr = 0; rr < 4; ++rr) {
                    int m = m0 + wr * 64 + mf * 16 + khi * 4 + rr;
                    Ofp[(size_t)m * 1024 + np] = acc[mf][nf][rr] + bb;
                }
            }
        }
    }
}

// ---------------------------------------------------------------------------
// pool_all: ALL 7 levels in one launch. 128 level-0 rows are self-contained
// for levels 1..7. Chain levels in fp32 LDS ping-pong (ref-accurate).
// blocks 0..2047: q/k  (tensor = bid>>10; bh = (bid&1023)>>5; seg = bid&31)
// blocks 2048..3071: v in d-major layout (pool along l within each d-row)
// ---------------------------------------------------------------------------
__global__ __launch_bounds__(256) void pool_all(
    const bfu* __restrict__ Qb, const bfu* __restrict__ Kb, const bfu* __restrict__ Vt0,
    bfu* __restrict__ Qp, bfu* __restrict__ Kp, bfu* __restrict__ Vtp)
{
    __shared__ bfu stg[8192];      // 16 KB: [128][64] (A) or [64][128] (B)
    __shared__ float buf0[4096];   // 16 KB fp32 ping
    __shared__ float buf1[4096];   // 16 KB fp32 pong
    const int bid = blockIdx.x;
    const int t = threadIdx.x;

    if (bid < 2048) {
        // ------- part A: q or k, row-major [l][d] -------
        const int tensor = bid >> 10;
        const int bh = (bid & 1023) >> 5, seg = bid & 31;
        const bfu* src = (tensor ? Kb : Qb) + ((size_t)bh * SEQL + seg * 128) * 64;
        bfu* dst = (tensor ? Kp : Qp) + (size_t)bh * PBH_POOL * 64;
        #pragma unroll
        for (int it = 0; it < 4; ++it) {
            int tt = it * 256 + t;             // 16B chunk: row=tt>>3, c8=tt&7
            *reinterpret_cast<uint4*>(&stg[(tt >> 3) * 64 + (tt & 7) * 8]) =
                *reinterpret_cast<const uint4*>(&src[(size_t)(tt >> 3) * 64 + (tt & 7) * 8]);
        }
        __syncthreads();
        // level 1: 64 rows x 64 d
        {
            int d = t & 63;
            #pragma unroll
            for (int i = 0; i < 16; ++i) {
                int r = (t >> 6) + 4 * i;
                float v = (b2f(stg[(2 * r) * 64 + d]) + b2f(stg[(2 * r + 1) * 64 + d])) * 0.5f;
                buf0[r * 64 + d] = v;
                dst[(size_t)(seg * 64 + r) * 64 + d] = f2b(v);   // dstRow0(1)=0
            }
        }
        __syncthreads();
        int nr = 32, dstRow0 = 2048;
        float* cur = buf0; float* nxt = buf1;
        for (int lvl = 2; lvl <= 7; ++lvl) {
            int elems = nr * 64;
            for (int i = t; i < elems; i += 256) {
                int r = i >> 6, dd = i & 63;
                float v = (cur[(2 * r) * 64 + dd] + cur[(2 * r + 1) * 64 + dd]) * 0.5f;
                nxt[r * 64 + dd] = v;
                dst[(size_t)(dstRow0 + seg * nr + r) * 64 + dd] = f2b(v);
            }
            __syncthreads();
            float* tmp = cur; cur = nxt; nxt = tmp;
            dstRow0 += 4096 >> lvl;
            nr >>= 1;
        }
    } else {
        // ------- part B: v, d-major [d][l] -------
        const int b2 = bid - 2048;
        const int bh = b2 >> 5, seg = b2 & 31;
        const bfu* src = Vt0 + (size_t)bh * 64 * SEQL + seg * 128;
        bfu* dst = Vtp + (size_t)bh * 64 * PBH_POOL;
        #pragma unroll
        for (int it = 0; it < 4; ++it) {
            int tt = it * 256 + t;             // 16B chunk: row=tt>>4, c8=tt&15
            *reinterpret_cast<uint4*>(&stg[(tt >> 4) * 128 + (tt & 15) * 8]) =
                *reinterpret_cast<const uint4*>(&src[(size_t)(tt >> 4) * SEQL + (tt & 15) * 8]);
        }
        __syncthreads();
        // level 1: 64 d-rows x 64 cols, SUM
        for (int i = t; i < 4096; i += 256) {
            int dd = i >> 6, c = i & 63;
            float v = b2f(stg[dd * 128 + 2 * c]) + b2f(stg[dd * 128 + 2 * c + 1]);
            buf0[dd * 64 + c] = v;
            dst[(size_t)dd * PBH_POOL + seg * 64 + c] = f2b(v);
        }
        __syncthreads();
        int nc = 32, lg = 5, dstRow0 = 2048;
        float* cur = buf0; float* nxt = buf1;
        for (int lvl = 2; lvl <= 7; ++lvl) {
            int elems = 64 * nc;
            for (int i = t; i < elems; i += 256) {
                int dd = i >> lg, c = i & (nc - 1);
                float v = cur[dd * 64 + 2 * c] + cur[dd * 64 + 2 * c + 1];
                nxt[dd * 64 + c] = v;
                dst[(size_t)dd * PBH_POOL + dstRow0 + seg * nc + c] = f2b(v);
            }
            __syncthreads();
            float* tmp = cur; cur = nxt; nxt = tmp;
            dstRow0 += 4096 >> lvl;
            nc >>= 1; --lg;
        }
    }
}

// ---------------------------------------------------------------------------
// pair_attn, 4 independent waves per block, one wave per (bh, block-pair).
// Direct global loads (race-free). S^T = K.Q^T via mfma_32x32x16;
// in-register softmax; PV with d-major V.
// ---------------------------------------------------------------------------
__global__ __launch_bounds__(256) void pair_attn(
    const bfu* __restrict__ Q0, const bfu* __restrict__ K0, const bfu* __restrict__ Vt0,
    const bfu* __restrict__ Qp, const bfu* __restrict__ Kp, const bfu* __restrict__ Vtp,
    bfu* __restrict__ y0, float* __restrict__ A0,
    bfu* __restrict__ ylev, float* __restrict__ Alev)
{
    const int bh = blockIdx.y;
    const int slot = blockIdx.x * 4 + (threadIdx.x >> 6);
    if (slot >= 255) return;
    int s = slot, lvl = 0, cnt = 128;
    while (s >= cnt) { s -= cnt; cnt >>= 1; ++lvl; }
    const bfu *Q, *K, *Vt; int perbh, vcols, loff;
    if (lvl == 0) { Q = Q0; K = K0; Vt = Vt0; perbh = SEQL; vcols = SEQL; loff = 0; }
    else { Q = Qp; K = Kp; Vt = Vtp; perbh = PBH_POOL; vcols = PBH_POOL; loff = 4096 - (8192 >> lvl); }
    const int rbase = loff + s * 32;
    const int t = threadIdx.x & 63, q31 = t & 31, hl = t >> 5;

    const bfu* Krow = K + ((size_t)bh * perbh + rbase + q31) * 64 + hl * 8;
    const bfu* Qrow = Q + ((size_t)bh * perbh + rbase + q31) * 64 + hl * 8;

    // S^T = K.Q^T  (C: col=lane&31=q, row kk=(reg&3)+8*(reg>>2)+4*(lane>>5))
    f32x16 S;
    #pragma unroll
    for (int e = 0; e < 16; ++e) S[e] = 0.f;
    #pragma unroll
    for (int db = 0; db < 4; ++db) {
        bf16x8 ka = *reinterpret_cast<const bf16x8*>(Krow + db * 16);
        bf16x8 qa = *reinterpret_cast<const bf16x8*>(Qrow + db * 16);
        S = __builtin_amdgcn_mfma_f32_32x32x16_bf16(ka, qa, S, 0, 0, 0);
    }

    float p[16];
    #pragma unroll
    for (int r = 0; r < 16; ++r) p[r] = S[r] * 0.125f;
    float mlo = p[0], mhi = p[8];
    #pragma unroll
    for (int r = 1; r < 8; ++r) { mlo = fmaxf(mlo, p[r]); mhi = fmaxf(mhi, p[r + 8]); }
    mlo = fmaxf(mlo, __shfl_xor(mlo, 32));
    mhi = fmaxf(mhi, __shfl_xor(mhi, 32));
    #pragma unroll
    for (int r = 0; r < 8; ++r) {
        p[r]     = __expf(p[r]     - mlo);
        p[r + 8] = __expf(p[r + 8] - mhi);
    }
    if (lvl > 0) {
        #pragma unroll
        for (int r = 0; r < 8; ++r) {
            if (q31 < 16) p[r] = 0.f; else p[r + 8] = 0.f;
        }
    }
    float alo = 0.f, ahi = 0.f;
    #pragma unroll
    for (int r = 0; r < 8; ++r) { alo += p[r]; ahi += p[r + 8]; }
    alo += __shfl_xor(alo, 32);
    ahi += __shfl_xor(ahi, 32);
    const float Asum = alo + ahi;

    // pack P^T into MFMA B operands (lane: col=q, k = kk = 16m + hl*8 + e)
    bf16x8 Pop[2];
    #pragma unroll
    for (int m = 0; m < 2; ++m) {
        u32 a0 = pk2(p[8 * m + 0], p[8 * m + 1]);
        u32 a1 = pk2(p[8 * m + 2], p[8 * m + 3]);
        u32 b0 = pk2(p[8 * m + 4], p[8 * m + 5]);
        u32 b1 = pk2(p[8 * m + 6], p[8 * m + 7]);
        u32 pa0 = __shfl_xor(a0, 32), pa1 = __shfl_xor(a1, 32);
        u32 pb0 = __shfl_xor(b0, 32), pb1 = __shfl_xor(b1, 32);
        Pop[m] = (hl == 0) ? mk8(a0, a1, pa0, pa1) : mk8(pb0, pb1, b0, b1);
    }

    // y^T = V^T.P^T with V in d-major layout -> each lane owns one y row
    const bfu* Vbase = Vt + (size_t)bh * 64 * vcols + rbase + hl * 8;
    f32x16 y[2];
    #pragma unroll
    for (int tt = 0; tt < 2; ++tt) {
        #pragma unroll
        for (int e = 0; e < 16; ++e) y[tt][e] = 0.f;
        #pragma unroll
        for (int m = 0; m < 2; ++m) {
            bf16x8 va = *reinterpret_cast<const bf16x8*>(
                Vbase + (size_t)(tt * 32 + q31) * vcols + m * 16);
            y[tt] = __builtin_amdgcn_mfma_f32_32x32x16_bf16(va, Pop[m], y[tt], 0, 0, 0);
        }
    }

    if (lvl == 0) {
        const int b = bh >> 4, h = bh & 15;
        bfu* orow = y0 + ((size_t)(b * SEQL + rbase + q31)) * 1024 + h * 64;
        #pragma unroll
        for (int tt = 0; tt < 2; ++tt)
            #pragma unroll
            for (int g = 0; g < 4; ++g) {
                int d0 = tt * 32 + g * 8 + hl * 4;
                ushort4 s4;
                s4.x = f2b(y[tt][4 * g + 0]); s4.y = f2b(y[tt][4 * g + 1]);
                s4.z = f2b(y[tt][4 * g + 2]); s4.w = f2b(y[tt][4 * g + 3]);
                *reinterpret_cast<ushort4*>(orow + d0) = s4;
            }
        if (hl == 0) A0[(size_t)bh * SEQL + rbase + q31] = Asum;
    } else {
        bfu* orow = ylev + ((size_t)bh * PBH_POOL + rbase + q31) * 64;
        #pragma unroll
        for (int tt = 0; tt < 2; ++tt)
            #pragma unroll
            for (int g = 0; g < 4; ++g) {
                int d0 = tt * 32 + g * 8 + hl * 4;
                ushort4 s4;
                s4.x = f2b(y[tt][4 * g + 0]); s4.y = f2b(y[tt][4 * g + 1]);
                s4.z = f2b(y[tt][4 * g + 2]); s4.w = f2b(y[tt][4 * g + 3]);
                *reinterpret_cast<ushort4*>(orow + d0) = s4;
            }
        if (hl == 0) Alev[(size_t)bh * PBH_POOL + rbase + q31] = Asum;
    }
}

// ---------------------------------------------------------------------------
// In-place: attn = (y0 + sum_levels ylev) / (A0 + sum Alev + eps), bf16.
// 4 d-elements per thread (A-sum loads amortized x4).
// ---------------------------------------------------------------------------
__global__ __launch_bounds__(256) void gather_norm(
    const bfu* __restrict__ ylev, const float* __restrict__ Alev,
    const float* __restrict__ A0, bfu* __restrict__ y0)
{
    size_t idx = ((size_t)blockIdx.x * 256 + threadIdx.x) * 4;
    int d0 = (int)(idx & 63);
    int h = (int)((idx >> 6) & 15);
    int l = (int)((idx >> 10) & 4095);
    int b = (int)(idx >> 22);
    int bh = b * NHEADS + h;

    ushort4 y4 = *reinterpret_cast<const ushort4*>(&y0[idx]);
    float ys0 = b2f(y4.x), ys1 = b2f(y4.y), ys2 = b2f(y4.z), ys3 = b2f(y4.w);
    float as = A0[(size_t)bh * SEQL + l];
    #pragma unroll
    for (int lvl = 1; lvl <= 7; ++lvl) {
        int r = (4096 - (8192 >> lvl)) + (l >> lvl);
        ushort4 v4 = *reinterpret_cast<const ushort4*>(
            &ylev[((size_t)bh * PBH_POOL + r) * 64 + d0]);
        ys0 += b2f(v4.x); ys1 += b2f(v4.y); ys2 += b2f(v4.z); ys3 += b2f(v4.w);
        as += Alev[(size_t)bh * PBH_POOL + r];
    }
    float inv = 1.0f / (as + 1e-12f);
    ushort4 o;
    o.x = f2b(ys0 * inv); o.y = f2b(ys1 * inv); o.z = f2b(ys2 * inv); o.w = f2b(ys3 * inv);
    *reinterpret_cast<ushort4*>(&y0[idx]) = o;
}

// ---------------------------------------------------------------------------
extern "C" void kernel_launch(void* const* d_in, const int* in_sizes, int n_in,
                              void* d_out, int out_size, void* d_ws, size_t ws_size,
                              hipStream_t stream)
{
    const float* q  = (const float*)d_in[0];
    const float* Wq = (const float*)d_in[1];
    const float* Wk = (const float*)d_in[2];
    const float* Wv = (const float*)d_in[3];
    const float* Wo = (const float*)d_in[4];
    const float* bo = (const float*)d_in[5];
    float* out = (float*)d_out;

    // workspace: ~143.1 MiB
    const size_t NE0 = (size_t)NBH * SEQL * 64;      // 8,388,608
    const size_t NEP = (size_t)NBH * PBH_POOL * 64;  // 8,323,072
    bfu* qb   = (bfu*)d_ws;            // q bf16; later y0/attn
    bfu* Wt   = qb + NE0;              // 4 transposed weights
    bfu* Qb   = Wt + 4 * 1048576;
    bfu* Kb   = Qb + NE0;
    bfu* Vt0  = Kb + NE0;              // d-major level-0 V (written by GEMM)
    bfu* Qp   = Vt0 + NE0;
    bfu* Kp   = Qp + NEP;
    bfu* Vtp  = Kp + NEP;
    bfu* ylev = Vtp + NEP;
    float* Alev = (float*)(ylev + NEP);              // 32*4064
    float* A0   = Alev + (size_t)NBH * PBH_POOL;     // 32*4096

    prep<<<12288, 256, 0, stream>>>(q, Wq, Wk, Wv, Wo, qb, Wt);

    // fused QKV; V written directly transposed into Vt0
    gemm_mfma<0><<<dim3(24, 64), 256, 0, stream>>>(
        qb, Wt, Qb, Kb, Vt0, nullptr, nullptr);

    pool_all<<<3072, 256, 0, stream>>>(Qb, Kb, Vt0, Qp, Kp, Vtp);

    pair_attn<<<dim3(64, NBH), 256, 0, stream>>>(
        Qb, Kb, Vt0, Qp, Kp, Vtp, qb /*y0*/, A0, ylev, Alev);

    gather_norm<<<8192, 256, 0, stream>>>(ylev, Alev, A0, qb);

    gemm_mfma<1><<<dim3(8, 64), 256, 0, stream>>>(
        qb, Wt + 3 * 1048576, nullptr, nullptr, nullptr, out, bo);
}